// Round 11
// baseline (650.669 us; speedup 1.0000x reference)
//
#include <hip/hip_runtime.h>
#include <hip/hip_bf16.h>
#include <math.h>

// GraphEncoder: 3x GCNConv (relu) -> global_mean_pool -> two linear heads.
// N=100000, E=1600000, G=2048, feats 10->128->256->256->64(x2)
//
// Round-11 = round-10 with the nt-store compile fix (ext_vector_type, not
// HIP_vector_type).
//  - 16-col feature slices (3.2MB fits 4MiB per-XCD L2; round-9's 32-col
//    slices were 6.4MB -> never resident). blockIdx%8 pins slice->XCD.
//    agg256 split into two kernels (slices 0-7 / 8-15).
//  - ALL activations slice-major [C/16][n][16]: agg stores contiguous per
//    slice (nt, full lines); transform A-loads 32B stride; pool reads sliced.
//    Accumulation order unchanged -> bit-identical output.

#define THREADS 256

typedef __attribute__((ext_vector_type(8))) short bf16x8;
typedef __attribute__((ext_vector_type(4))) float f32x4;
typedef __attribute__((ext_vector_type(4))) unsigned u32x4;

// ---------------- fused setup: deg=1, W2T, W3T ----------------
__global__ void setup_kernel(int* deg,
                             const float* __restrict__ W2, __hip_bfloat16* __restrict__ W2T,
                             const float* __restrict__ W3, __hip_bfloat16* __restrict__ W3T,
                             int n) {
    int i = blockIdx.x * blockDim.x + threadIdx.x;
    if (i < n) deg[i] = 1;                       // self-loop
    int r2 = i - n;
    if (r2 >= 0 && r2 < 128 * 256) {
        int k = r2 >> 8, c = r2 & 255;
        W2T[c * 128 + k] = __float2bfloat16(W2[r2]);
    }
    int r3 = i - n - 128 * 256;
    if (r3 >= 0 && r3 < 256 * 256) {
        int k = r3 >> 8, c = r3 & 255;
        W3T[c * 256 + k] = __float2bfloat16(W3[r3]);
    }
}

// ---------------- indegree hist + goff from sorted-batch boundaries ----------------
__global__ void hist_bound_kernel(const int* __restrict__ dst, int* deg, int e,
                                  const int* __restrict__ batch, int* goff,
                                  int n, int g) {
    int i = blockIdx.x * blockDim.x + threadIdx.x;
    if (i < e) {
        atomicAdd(&deg[dst[i]], 1);
    } else {
        int j = i - e;
        if (j < n) {
            int b = batch[j];
            if (j == 0) {
                for (int q = 0; q <= b; ++q) goff[q] = 0;
            } else {
                int bp = batch[j - 1];
                for (int q = bp + 1; q <= b; ++q) goff[q] = j;
            }
            if (j == n - 1) {
                for (int q = b + 1; q <= g; ++q) goff[q] = n;
            }
        }
    }
}

// ---------------- single-phase scan: row_ptr (+cursor, +dis) ----------------
__global__ __launch_bounds__(1024) void scan_deg_kernel(
        const int* __restrict__ deg, int* __restrict__ row_ptr,
        int* __restrict__ cursor, float* __restrict__ dis, int n) {
    __shared__ int wsum[16];
    int carry = 0;
    const int lane = threadIdx.x & 63;
    const int wid = threadIdx.x >> 6;
    for (int base = 0; base < n; base += 4096) {
        int i0 = base + threadIdx.x * 4;
        int v[4];
#pragma unroll
        for (int q = 0; q < 4; ++q) {
            int i = i0 + q;
            v[q] = (i < n) ? (deg[i] - 1) : 0;   // indegree
        }
        int tsum = v[0] + v[1] + v[2] + v[3];
        int incl = tsum;
#pragma unroll
        for (int off = 1; off < 64; off <<= 1) {
            int t = __shfl_up(incl, off, 64);
            if (lane >= off) incl += t;
        }
        if (lane == 63) wsum[wid] = incl;
        __syncthreads();
        int wbase = 0;
        for (int w = 0; w < wid; ++w) wbase += wsum[w];
        int pos = incl - tsum + wbase + carry;
#pragma unroll
        for (int q = 0; q < 4; ++q) {
            int i = i0 + q;
            if (i < n) {
                row_ptr[i] = pos;
                cursor[i] = pos;
                dis[i] = rsqrtf((float)(v[q] + 1));
            }
            pos += v[q];
        }
        int tot = 0;
        for (int w = 0; w < 16; ++w) tot += wsum[w];
        carry += tot;
        __syncthreads();
    }
    if (threadIdx.x == 0) row_ptr[n] = carry;
}

// ---------------- dst-sliced CSR fill (4 slices) ----------------
__global__ __launch_bounds__(THREADS) void fill_csr_kernel(
        const int* __restrict__ src, const int* __restrict__ dst,
        int* cursor, int* __restrict__ col, int e, int n) {
    const int nslice = 4;
    const int sliceSize = (n + nslice - 1) / nslice;
    const int tid = blockIdx.x * blockDim.x + threadIdx.x;
    const int nthr = gridDim.x * blockDim.x;
    for (int s = 0; s < nslice; ++s) {
        const int lo = s * sliceSize;
        const int hi = lo + sliceSize;
        for (int i = tid; i < e; i += nthr) {
            int d = dst[i];
            if (d >= lo && d < hi) {
                int pos = atomicAdd(&cursor[d], 1);
                col[pos] = src[i];
            }
        }
    }
}

// ---------------- bf16 helpers ----------------
__device__ __forceinline__ void acc8(float* acc, uint4 v) {
    acc[0] += __uint_as_float(v.x << 16);
    acc[1] += __uint_as_float(v.x & 0xffff0000u);
    acc[2] += __uint_as_float(v.y << 16);
    acc[3] += __uint_as_float(v.y & 0xffff0000u);
    acc[4] += __uint_as_float(v.z << 16);
    acc[5] += __uint_as_float(v.z & 0xffff0000u);
    acc[6] += __uint_as_float(v.w << 16);
    acc[7] += __uint_as_float(v.w & 0xffff0000u);
}

__device__ __forceinline__ unsigned pack2(float a, float b) {
    unsigned short ua = __builtin_bit_cast(unsigned short, __float2bfloat16(a));
    unsigned short ub = __builtin_bit_cast(unsigned short, __float2bfloat16(b));
    return (unsigned)ua | ((unsigned)ub << 16);
}

// ---------------- fused layer 1: agg over 10-col x rows + 10->128 transform ----------------
// Output slice-major [8][n][16] (source of agg128's sliced gather).
__global__ __launch_bounds__(THREADS) void layer1_kernel(
        const float* __restrict__ x, const int* __restrict__ row_ptr,
        const int* __restrict__ col, const float* __restrict__ dis,
        const float* __restrict__ W1, const float* __restrict__ b1,
        __hip_bfloat16* __restrict__ out, int n) {
    __shared__ float h[16][12];
    __shared__ float w[10][128];
    __shared__ float bias[128];

    for (int idx = threadIdx.x; idx < 1280; idx += THREADS)
        w[idx >> 7][idx & 127] = W1[idx];
    if (threadIdx.x < 128) bias[threadIdx.x] = b1[threadIdx.x];

    const int node0 = blockIdx.x * 16;
    const int sub = threadIdx.x >> 4;
    const int lane = threadIdx.x & 15;
    const int node = node0 + sub;
    const bool act = (lane < 10) && (node < n);

    float acc = 0.f;
    float dn = 1.f;
    if (act) {
        dn = dis[node];
        acc = x[(size_t)node * 10 + lane] * dn;
        int s = row_ptr[node], e = row_ptr[node + 1];
        int p = s;
        for (; p + 8 <= e; p += 8) {
            int j[8];
#pragma unroll
            for (int q = 0; q < 8; ++q) j[q] = col[p + q];
            float v[8];
#pragma unroll
            for (int q = 0; q < 8; ++q) v[q] = x[(size_t)j[q] * 10 + lane] * dis[j[q]];
#pragma unroll
            for (int q = 0; q < 8; ++q) acc += v[q];
        }
        for (; p < e; ++p) {
            int j = col[p];
            acc += x[(size_t)j * 10 + lane] * dis[j];
        }
        acc *= dn;
    }
    if (lane < 12) h[sub][lane] = (lane < 10) ? acc : 0.f;
    __syncthreads();

    const int r = threadIdx.x >> 4;
    const int c0 = (threadIdx.x & 15) * 8;       // 8 cols = 1 uint4
    const int nodeB = node0 + r;
    if (nodeB < n) {
        float dnB = dis[nodeB];
        float hv[10];
#pragma unroll
        for (int k = 0; k < 10; ++k) hv[k] = h[r][k];
        uint4 res;
        unsigned rr[4];
#pragma unroll
        for (int cc = 0; cc < 8; cc += 2) {
            float a0 = bias[c0 + cc], a1 = bias[c0 + cc + 1];
#pragma unroll
            for (int k = 0; k < 10; ++k) {
                a0 = fmaf(hv[k], w[k][c0 + cc], a0);
                a1 = fmaf(hv[k], w[k][c0 + cc + 1], a1);
            }
            rr[cc >> 1] = pack2(fmaxf(a0, 0.f) * dnB, fmaxf(a1, 0.f) * dnB);
        }
        res.x = rr[0]; res.y = rr[1]; res.z = rr[2]; res.w = rr[3];
        // slice-major [8][n][16]: slice = c0/16, half = (c0/8)&1
        size_t idx = (size_t)(c0 >> 4) * ((size_t)n * 2) + (size_t)nodeB * 2 + ((c0 >> 3) & 1);
        reinterpret_cast<uint4*>(out)[idx] = res;
    }
}

// ---------------- XCD-sliced agg, 16-col slices (3.2MB, L2-resident) ----------
// S, out both slice-major [C/16][n][16]. blockIdx%8 + SOFF = slice (XCD-pinned).
// nt stores keep the output stream from evicting the resident slice.
template <int SOFF>
__global__ __launch_bounds__(THREADS) void agg_slice16_kernel(
        const __hip_bfloat16* __restrict__ S, const int* __restrict__ row_ptr,
        const int* __restrict__ col, const float* __restrict__ dis,
        __hip_bfloat16* __restrict__ out, int n) {
    const int slice = (blockIdx.x & 7) + SOFF;
    const int grp = blockIdx.x >> 3;
    const int sub = threadIdx.x >> 1;
    const int lane = threadIdx.x & 1;
    const int node = grp * 128 + sub;
    if (node >= n) return;

    const uint4* S4 = reinterpret_cast<const uint4*>(S);
    const size_t sbase = (size_t)slice * ((size_t)n * 2);

    float acc[8];
#pragma unroll
    for (int q = 0; q < 8; ++q) acc[q] = 0.f;
    acc8(acc, S4[sbase + (size_t)node * 2 + lane]);   // self-loop term

    int s = row_ptr[node], e = row_ptr[node + 1];
    int p = s;
    for (; p + 8 <= e; p += 8) {
        int j[8];
#pragma unroll
        for (int q = 0; q < 8; ++q) j[q] = col[p + q];
        uint4 v[8];
#pragma unroll
        for (int q = 0; q < 8; ++q) v[q] = S4[sbase + (size_t)j[q] * 2 + lane];
#pragma unroll
        for (int q = 0; q < 8; ++q) acc8(acc, v[q]);
    }
    for (; p + 2 <= e; p += 2) {
        int j0 = col[p], j1 = col[p + 1];
        uint4 v0 = S4[sbase + (size_t)j0 * 2 + lane];
        uint4 v1 = S4[sbase + (size_t)j1 * 2 + lane];
        acc8(acc, v0); acc8(acc, v1);
    }
    for (; p < e; ++p) acc8(acc, S4[sbase + (size_t)col[p] * 2 + lane]);

    float d = dis[node];
    u32x4 o;
    o.x = pack2(acc[0] * d, acc[1] * d);
    o.y = pack2(acc[2] * d, acc[3] * d);
    o.z = pack2(acc[4] * d, acc[5] * d);
    o.w = pack2(acc[6] * d, acc[7] * d);
    // slice-major out, consecutive threads -> consecutive 16B (full lines)
    __builtin_nontemporal_store(o,
        reinterpret_cast<u32x4*>(out) + sbase + (size_t)node * 2 + lane);
}

// ---------------- MFMA transform: slice-major A [K/16][n][16] -> slice-major out ----
template <int K, bool SCALE>
__global__ __launch_bounds__(THREADS) void transform_mfma2_kernel(
        const __hip_bfloat16* __restrict__ A, const __hip_bfloat16* __restrict__ WT,
        const float* __restrict__ b, const float* __restrict__ dis,
        __hip_bfloat16* __restrict__ out, int n, int ntiles) {
    constexpr int KS = K / 32;             // 4 (K=128) or 8 (K=256)
    const int wave = threadIdx.x >> 6;
    const int lane = threadIdx.x & 63;
    const int lrow = lane & 15;
    const int lk8  = (lane >> 4) * 8;      // k-element offset within a 32-k step

    const uint4* WT4 = reinterpret_cast<const uint4*>(WT);
    bf16x8 bfr[4][KS];
    float bias[4];
#pragma unroll
    for (int ct = 0; ct < 4; ++ct) {
        int colc = wave * 64 + ct * 16 + lrow;
        bias[ct] = b[colc];
#pragma unroll
        for (int kk = 0; kk < KS; ++kk)
            bfr[ct][kk] = __builtin_bit_cast(
                bf16x8, WT4[((size_t)colc * K + kk * 32 + lk8) >> 3]);
    }

    const uint4* A4 = reinterpret_cast<const uint4*>(A);
    auto loadA = [&](int t, uint4* av) {
        int row = t * 16 + lrow;
        if (row >= n) row = n - 1;
#pragma unroll
        for (int kk = 0; kk < KS; ++kk) {
            int c = kk * 32 + lk8;       // multiple of 8
            av[kk] = A4[(size_t)(c >> 4) * ((size_t)n * 2) + (size_t)row * 2 + ((c >> 3) & 1)];
        }
    };

    uint4 aC[KS], aN[KS];
    int t = blockIdx.x;
    if (t < ntiles) loadA(t, aC);

    for (; t < ntiles; t += gridDim.x) {
        int tn = t + gridDim.x;
        if (tn < ntiles) loadA(tn, aN);    // prefetch next tile

        f32x4 acc[4];
#pragma unroll
        for (int ct = 0; ct < 4; ++ct) acc[ct] = (f32x4){0.f, 0.f, 0.f, 0.f};
#pragma unroll
        for (int kk = 0; kk < KS; ++kk) {
            bf16x8 af = __builtin_bit_cast(bf16x8, aC[kk]);
#pragma unroll
            for (int ct = 0; ct < 4; ++ct)
                acc[ct] = __builtin_amdgcn_mfma_f32_16x16x32_bf16(af, bfr[ct][kk], acc[ct], 0, 0, 0);
        }

        const int orow0 = t * 16 + (lane >> 4) * 4;
        float dv[4];
#pragma unroll
        for (int r = 0; r < 4; ++r) {
            int rr = orow0 + r;
            dv[r] = SCALE ? ((rr < n) ? dis[rr] : 0.f) : 1.f;
        }
#pragma unroll
        for (int ct = 0; ct < 4; ++ct) {
            int colc = wave * 64 + ct * 16 + lrow;
#pragma unroll
            for (int r = 0; r < 4; ++r) {
                int rr = orow0 + r;
                if (rr < n) {
                    float v = fmaxf(acc[ct][r] + bias[ct], 0.f);
                    if (SCALE) v *= dv[r];
                    // slice-major [*/16][n][16]; 16 lanes -> 32B contiguous
                    out[(size_t)(colc >> 4) * ((size_t)n * 16) + (size_t)rr * 16 + (colc & 15)] =
                        __float2bfloat16(v);
                }
            }
        }
#pragma unroll
        for (int kk = 0; kk < KS; ++kk) aC[kk] = aN[kk];
    }
}

// ---------------- fused mean-pool + heads (slice-major input) ----------------
__global__ __launch_bounds__(THREADS) void pool_heads_kernel(
        const __hip_bfloat16* __restrict__ H, const int* __restrict__ goff,
        const float* __restrict__ Wmu, const float* __restrict__ bmu,
        const float* __restrict__ Wlv, const float* __restrict__ blv,
        float* __restrict__ out, int g_total, int n) {
    __shared__ float p[256];
    int g = blockIdx.x;
    int c = threadIdx.x;
    int s = goff[g], e = goff[g + 1];
    const __hip_bfloat16* Hs = H + (size_t)(c >> 4) * ((size_t)n * 16) + (c & 15);
    float acc = 0.f;
    for (int r = s; r < e; ++r) acc += __bfloat162float(Hs[(size_t)r * 16]);
    p[c] = acc / fmaxf((float)(e - s), 1.0f);
    __syncthreads();
    if (threadIdx.x < 128) {
        int cc = threadIdx.x & 63;
        bool is_mu = threadIdx.x < 64;
        const float* W = is_mu ? Wmu : Wlv;
        const float* bb = is_mu ? bmu : blv;
        float a = 0.f;
        for (int k = 0; k < 256; ++k) a = fmaf(p[k], W[k * 64 + cc], a);
        float* o = is_mu ? (out + (size_t)g * 64)
                         : (out + (size_t)g_total * 64 + (size_t)g * 64);
        o[cc] = a + bb[cc];
    }
}

extern "C" void kernel_launch(void* const* d_in, const int* in_sizes, int n_in,
                              void* d_out, int out_size, void* d_ws, size_t ws_size,
                              hipStream_t stream) {
    const float* x      = (const float*)d_in[0];
    const int*   eidx   = (const int*)d_in[1];
    const int*   batch  = (const int*)d_in[2];
    const float* W1  = (const float*)d_in[3];
    const float* b1  = (const float*)d_in[4];
    const float* W2  = (const float*)d_in[5];
    const float* b2  = (const float*)d_in[6];
    const float* W3  = (const float*)d_in[7];
    const float* b3  = (const float*)d_in[8];
    const float* Wmu = (const float*)d_in[9];
    const float* bmu = (const float*)d_in[10];
    const float* Wlv = (const float*)d_in[11];
    const float* blv = (const float*)d_in[12];
    float* out = (float*)d_out;

    const int N = in_sizes[0] / 10;
    const int E = in_sizes[1] / 2;
    const int G = out_size / 128;

    const int* src = eidx;       // edge_index[0]
    const int* dst = eidx + E;   // edge_index[1]

    // workspace carve-up (~118 MB)
    __hip_bfloat16* SA = (__hip_bfloat16*)d_ws;          // [N,256] bf16 ping (slice-major)
    __hip_bfloat16* SB = SA + (size_t)N * 256;           // [N,256] bf16 pong (slice-major)
    float* dis  = (float*)(SB + (size_t)N * 256);        // [N]
    __hip_bfloat16* W2T = (__hip_bfloat16*)(dis + N);    // [256][128]
    __hip_bfloat16* W3T = W2T + 256 * 128;               // [256][256]
    int* deg     = (int*)(W3T + 256 * 256);              // [N]
    int* row_ptr = deg + N;                              // [N+1]
    int* cursor  = row_ptr + N + 1;                      // [N]
    int* col     = cursor + N;                           // [E]
    int* goff    = col + E;                              // [G+1]

    const int ntiles = (N + 15) / 16;
    const int agg_grid = ((N + 127) / 128) * 8;

    // setup: deg=1, W transposes
    {
        int total = N + 128 * 256 + 256 * 256;
        setup_kernel<<<(total + THREADS - 1) / THREADS, THREADS, 0, stream>>>(
            deg, W2, W2T, W3, W3T, N);
    }
    // indegree hist + goff boundaries
    {
        int total = E + N;
        hist_bound_kernel<<<(total + THREADS - 1) / THREADS, THREADS, 0, stream>>>(
            dst, deg, E, batch, goff, N, G);
    }
    // scan: row_ptr (+cursor, +dis)
    scan_deg_kernel<<<1, 1024, 0, stream>>>(deg, row_ptr, cursor, dis, N);
    // dst-sliced CSR fill (4 slices)
    fill_csr_kernel<<<2048, THREADS, 0, stream>>>(src, dst, cursor, col, E, N);

    // layer 1: fused gather(x*dis) + 10->128 transform -> slice-major SA [8][N][16]
    layer1_kernel<<<(N + 15) / 16, THREADS, 0, stream>>>(
        x, row_ptr, col, dis, W1, b1, SA, N);

    // layer 2: sliced aggregate (8 slices) SA -> SB, MFMA 128->256 (*dis) -> SA [16][N][16]
    agg_slice16_kernel<0><<<agg_grid, THREADS, 0, stream>>>(SA, row_ptr, col, dis, SB, N);
    transform_mfma2_kernel<128, true><<<512, THREADS, 0, stream>>>(
        SB, W2T, b2, dis, SA, N, ntiles);

    // layer 3: sliced aggregate (16 slices, two 8-slice kernels) SA -> SB,
    //          MFMA 256->256 -> SA [16][N][16]
    agg_slice16_kernel<0><<<agg_grid, THREADS, 0, stream>>>(SA, row_ptr, col, dis, SB, N);
    agg_slice16_kernel<8><<<agg_grid, THREADS, 0, stream>>>(SA, row_ptr, col, dis, SB, N);
    transform_mfma2_kernel<256, false><<<512, THREADS, 0, stream>>>(
        SB, W3T, b3, dis, SA, N, ntiles);

    // fused mean pool + heads (slice-major input)
    pool_heads_kernel<<<G, THREADS, 0, stream>>>(SA, goff, Wmu, bmu, Wlv, blv, out, G, N);
}

// Round 12
// 640.683 us; speedup vs baseline: 1.0156x; 1.0156x over previous
//
#include <hip/hip_runtime.h>
#include <hip/hip_bf16.h>
#include <math.h>

// GraphEncoder: 3x GCNConv (relu) -> global_mean_pool -> two linear heads.
// N=100000, E=1600000, G=2048, feats 10->128->256->256->64(x2)
//
// Round-12 strategy:
//  - fill_csr: XCD-PINNED 8 concurrent dst-slices (blockIdx&7 = slice = XCD).
//    Round-11 showed WRITE_SIZE=102MB persists with sequential slicing: each
//    line was partially dirtied by all 8 XCD L2s -> 8 partial writebacks.
//    Disjoint dst-range per XCD -> single full-line writeback per col line.
//  - layer1 phase-B remap: thread=slice*16+row, full 32B slice-row per thread
//    -> 512B contiguous stores (round-11 scattered 16B chunks across slices).
//  - rest identical to round 11 (so next profile exposes sliced-agg times).

#define THREADS 256

typedef __attribute__((ext_vector_type(8))) short bf16x8;
typedef __attribute__((ext_vector_type(4))) float f32x4;
typedef __attribute__((ext_vector_type(4))) unsigned u32x4;

// ---------------- fused setup: deg=1, W2T, W3T ----------------
__global__ void setup_kernel(int* deg,
                             const float* __restrict__ W2, __hip_bfloat16* __restrict__ W2T,
                             const float* __restrict__ W3, __hip_bfloat16* __restrict__ W3T,
                             int n) {
    int i = blockIdx.x * blockDim.x + threadIdx.x;
    if (i < n) deg[i] = 1;                       // self-loop
    int r2 = i - n;
    if (r2 >= 0 && r2 < 128 * 256) {
        int k = r2 >> 8, c = r2 & 255;
        W2T[c * 128 + k] = __float2bfloat16(W2[r2]);
    }
    int r3 = i - n - 128 * 256;
    if (r3 >= 0 && r3 < 256 * 256) {
        int k = r3 >> 8, c = r3 & 255;
        W3T[c * 256 + k] = __float2bfloat16(W3[r3]);
    }
}

// ---------------- indegree hist + goff from sorted-batch boundaries ----------------
__global__ void hist_bound_kernel(const int* __restrict__ dst, int* deg, int e,
                                  const int* __restrict__ batch, int* goff,
                                  int n, int g) {
    int i = blockIdx.x * blockDim.x + threadIdx.x;
    if (i < e) {
        atomicAdd(&deg[dst[i]], 1);
    } else {
        int j = i - e;
        if (j < n) {
            int b = batch[j];
            if (j == 0) {
                for (int q = 0; q <= b; ++q) goff[q] = 0;
            } else {
                int bp = batch[j - 1];
                for (int q = bp + 1; q <= b; ++q) goff[q] = j;
            }
            if (j == n - 1) {
                for (int q = b + 1; q <= g; ++q) goff[q] = n;
            }
        }
    }
}

// ---------------- single-phase scan: row_ptr (+cursor, +dis) ----------------
__global__ __launch_bounds__(1024) void scan_deg_kernel(
        const int* __restrict__ deg, int* __restrict__ row_ptr,
        int* __restrict__ cursor, float* __restrict__ dis, int n) {
    __shared__ int wsum[16];
    int carry = 0;
    const int lane = threadIdx.x & 63;
    const int wid = threadIdx.x >> 6;
    for (int base = 0; base < n; base += 4096) {
        int i0 = base + threadIdx.x * 4;
        int v[4];
#pragma unroll
        for (int q = 0; q < 4; ++q) {
            int i = i0 + q;
            v[q] = (i < n) ? (deg[i] - 1) : 0;   // indegree
        }
        int tsum = v[0] + v[1] + v[2] + v[3];
        int incl = tsum;
#pragma unroll
        for (int off = 1; off < 64; off <<= 1) {
            int t = __shfl_up(incl, off, 64);
            if (lane >= off) incl += t;
        }
        if (lane == 63) wsum[wid] = incl;
        __syncthreads();
        int wbase = 0;
        for (int w = 0; w < wid; ++w) wbase += wsum[w];
        int pos = incl - tsum + wbase + carry;
#pragma unroll
        for (int q = 0; q < 4; ++q) {
            int i = i0 + q;
            if (i < n) {
                row_ptr[i] = pos;
                cursor[i] = pos;
                dis[i] = rsqrtf((float)(v[q] + 1));
            }
            pos += v[q];
        }
        int tot = 0;
        for (int w = 0; w < 16; ++w) tot += wsum[w];
        carry += tot;
        __syncthreads();
    }
    if (threadIdx.x == 0) row_ptr[n] = carry;
}

// ---------------- XCD-pinned CSR fill: blockIdx&7 = dst-slice = XCD ----------
// Disjoint dst ranges per slice -> each col/cursor line has ONE writer XCD ->
// full-line writebacks (round-11: cross-XCD partial dirty lines = 102MB).
__global__ __launch_bounds__(THREADS) void fill_csr_kernel(
        const int* __restrict__ src, const int* __restrict__ dst,
        int* cursor, int* __restrict__ col, int e, int n) {
    const int slice = blockIdx.x & 7;
    const int sliceSize = (n + 7) / 8;
    const int lo = slice * sliceSize;
    const int hi = lo + sliceSize;
    const int tid = (blockIdx.x >> 3) * blockDim.x + threadIdx.x;
    const int nthr = (gridDim.x >> 3) * blockDim.x;
    for (int i = tid; i < e; i += nthr) {
        int d = dst[i];
        if (d >= lo && d < hi) {
            int pos = atomicAdd(&cursor[d], 1);
            col[pos] = src[i];
        }
    }
}

// ---------------- bf16 helpers ----------------
__device__ __forceinline__ void acc8(float* acc, uint4 v) {
    acc[0] += __uint_as_float(v.x << 16);
    acc[1] += __uint_as_float(v.x & 0xffff0000u);
    acc[2] += __uint_as_float(v.y << 16);
    acc[3] += __uint_as_float(v.y & 0xffff0000u);
    acc[4] += __uint_as_float(v.z << 16);
    acc[5] += __uint_as_float(v.z & 0xffff0000u);
    acc[6] += __uint_as_float(v.w << 16);
    acc[7] += __uint_as_float(v.w & 0xffff0000u);
}

__device__ __forceinline__ unsigned pack2(float a, float b) {
    unsigned short ua = __builtin_bit_cast(unsigned short, __float2bfloat16(a));
    unsigned short ub = __builtin_bit_cast(unsigned short, __float2bfloat16(b));
    return (unsigned)ua | ((unsigned)ub << 16);
}

// ---------------- fused layer 1: agg over 10-col x rows + 10->128 transform ----------------
// Output slice-major [8][n][16]. Phase B: thread = slice*16 + row, each writes
// a full 32B slice-row -> 512B contiguous per 16-thread group.
__global__ __launch_bounds__(THREADS) void layer1_kernel(
        const float* __restrict__ x, const int* __restrict__ row_ptr,
        const int* __restrict__ col, const float* __restrict__ dis,
        const float* __restrict__ W1, const float* __restrict__ b1,
        __hip_bfloat16* __restrict__ out, int n) {
    __shared__ float h[16][12];
    __shared__ float w[10][128];
    __shared__ float bias[128];

    for (int idx = threadIdx.x; idx < 1280; idx += THREADS)
        w[idx >> 7][idx & 127] = W1[idx];
    if (threadIdx.x < 128) bias[threadIdx.x] = b1[threadIdx.x];

    const int node0 = blockIdx.x * 16;
    const int sub = threadIdx.x >> 4;
    const int lane = threadIdx.x & 15;
    const int node = node0 + sub;
    const bool act = (lane < 10) && (node < n);

    float acc = 0.f;
    float dn = 1.f;
    if (act) {
        dn = dis[node];
        acc = x[(size_t)node * 10 + lane] * dn;
        int s = row_ptr[node], e = row_ptr[node + 1];
        int p = s;
        for (; p + 8 <= e; p += 8) {
            int j[8];
#pragma unroll
            for (int q = 0; q < 8; ++q) j[q] = col[p + q];
            float v[8];
#pragma unroll
            for (int q = 0; q < 8; ++q) v[q] = x[(size_t)j[q] * 10 + lane] * dis[j[q]];
#pragma unroll
            for (int q = 0; q < 8; ++q) acc += v[q];
        }
        for (; p < e; ++p) {
            int j = col[p];
            acc += x[(size_t)j * 10 + lane] * dis[j];
        }
        acc *= dn;
    }
    if (lane < 12) h[sub][lane] = (lane < 10) ? acc : 0.f;
    __syncthreads();

    if (threadIdx.x < 128) {
        const int slice = threadIdx.x >> 4;   // 0..7
        const int r = threadIdx.x & 15;
        const int nodeB = node0 + r;
        if (nodeB < n) {
            float dnB = dis[nodeB];
            float hv[10];
#pragma unroll
            for (int k = 0; k < 10; ++k) hv[k] = h[r][k];
            unsigned rr[8];
#pragma unroll
            for (int cc = 0; cc < 16; cc += 2) {
                int c = slice * 16 + cc;
                float a0 = bias[c], a1 = bias[c + 1];
#pragma unroll
                for (int k = 0; k < 10; ++k) {
                    a0 = fmaf(hv[k], w[k][c], a0);
                    a1 = fmaf(hv[k], w[k][c + 1], a1);
                }
                rr[cc >> 1] = pack2(fmaxf(a0, 0.f) * dnB, fmaxf(a1, 0.f) * dnB);
            }
            uint4 res0 = make_uint4(rr[0], rr[1], rr[2], rr[3]);
            uint4 res1 = make_uint4(rr[4], rr[5], rr[6], rr[7]);
            size_t base = (size_t)slice * ((size_t)n * 2) + (size_t)nodeB * 2;
            reinterpret_cast<uint4*>(out)[base] = res0;
            reinterpret_cast<uint4*>(out)[base + 1] = res1;
        }
    }
}

// ---------------- XCD-sliced agg, 16-col slices (3.2MB, L2-resident) ----------
// S, out both slice-major [C/16][n][16]. blockIdx%8 + SOFF = slice (XCD-pinned).
template <int SOFF>
__global__ __launch_bounds__(THREADS) void agg_slice16_kernel(
        const __hip_bfloat16* __restrict__ S, const int* __restrict__ row_ptr,
        const int* __restrict__ col, const float* __restrict__ dis,
        __hip_bfloat16* __restrict__ out, int n) {
    const int slice = (blockIdx.x & 7) + SOFF;
    const int grp = blockIdx.x >> 3;
    const int sub = threadIdx.x >> 1;
    const int lane = threadIdx.x & 1;
    const int node = grp * 128 + sub;
    if (node >= n) return;

    const uint4* S4 = reinterpret_cast<const uint4*>(S);
    const size_t sbase = (size_t)slice * ((size_t)n * 2);

    float acc[8];
#pragma unroll
    for (int q = 0; q < 8; ++q) acc[q] = 0.f;
    acc8(acc, S4[sbase + (size_t)node * 2 + lane]);   // self-loop term

    int s = row_ptr[node], e = row_ptr[node + 1];
    int p = s;
    for (; p + 8 <= e; p += 8) {
        int j[8];
#pragma unroll
        for (int q = 0; q < 8; ++q) j[q] = col[p + q];
        uint4 v[8];
#pragma unroll
        for (int q = 0; q < 8; ++q) v[q] = S4[sbase + (size_t)j[q] * 2 + lane];
#pragma unroll
        for (int q = 0; q < 8; ++q) acc8(acc, v[q]);
    }
    for (; p + 2 <= e; p += 2) {
        int j0 = col[p], j1 = col[p + 1];
        uint4 v0 = S4[sbase + (size_t)j0 * 2 + lane];
        uint4 v1 = S4[sbase + (size_t)j1 * 2 + lane];
        acc8(acc, v0); acc8(acc, v1);
    }
    for (; p < e; ++p) acc8(acc, S4[sbase + (size_t)col[p] * 2 + lane]);

    float d = dis[node];
    u32x4 o;
    o.x = pack2(acc[0] * d, acc[1] * d);
    o.y = pack2(acc[2] * d, acc[3] * d);
    o.z = pack2(acc[4] * d, acc[5] * d);
    o.w = pack2(acc[6] * d, acc[7] * d);
    __builtin_nontemporal_store(o,
        reinterpret_cast<u32x4*>(out) + sbase + (size_t)node * 2 + lane);
}

// ---------------- MFMA transform: slice-major A [K/16][n][16] -> slice-major out ----
template <int K, bool SCALE>
__global__ __launch_bounds__(THREADS) void transform_mfma2_kernel(
        const __hip_bfloat16* __restrict__ A, const __hip_bfloat16* __restrict__ WT,
        const float* __restrict__ b, const float* __restrict__ dis,
        __hip_bfloat16* __restrict__ out, int n, int ntiles) {
    constexpr int KS = K / 32;             // 4 (K=128) or 8 (K=256)
    const int wave = threadIdx.x >> 6;
    const int lane = threadIdx.x & 63;
    const int lrow = lane & 15;
    const int lk8  = (lane >> 4) * 8;      // k-element offset within a 32-k step

    const uint4* WT4 = reinterpret_cast<const uint4*>(WT);
    bf16x8 bfr[4][KS];
    float bias[4];
#pragma unroll
    for (int ct = 0; ct < 4; ++ct) {
        int colc = wave * 64 + ct * 16 + lrow;
        bias[ct] = b[colc];
#pragma unroll
        for (int kk = 0; kk < KS; ++kk)
            bfr[ct][kk] = __builtin_bit_cast(
                bf16x8, WT4[((size_t)colc * K + kk * 32 + lk8) >> 3]);
    }

    const uint4* A4 = reinterpret_cast<const uint4*>(A);
    auto loadA = [&](int t, uint4* av) {
        int row = t * 16 + lrow;
        if (row >= n) row = n - 1;
#pragma unroll
        for (int kk = 0; kk < KS; ++kk) {
            int c = kk * 32 + lk8;       // multiple of 8
            av[kk] = A4[(size_t)(c >> 4) * ((size_t)n * 2) + (size_t)row * 2 + ((c >> 3) & 1)];
        }
    };

    uint4 aC[KS], aN[KS];
    int t = blockIdx.x;
    if (t < ntiles) loadA(t, aC);

    for (; t < ntiles; t += gridDim.x) {
        int tn = t + gridDim.x;
        if (tn < ntiles) loadA(tn, aN);    // prefetch next tile

        f32x4 acc[4];
#pragma unroll
        for (int ct = 0; ct < 4; ++ct) acc[ct] = (f32x4){0.f, 0.f, 0.f, 0.f};
#pragma unroll
        for (int kk = 0; kk < KS; ++kk) {
            bf16x8 af = __builtin_bit_cast(bf16x8, aC[kk]);
#pragma unroll
            for (int ct = 0; ct < 4; ++ct)
                acc[ct] = __builtin_amdgcn_mfma_f32_16x16x32_bf16(af, bfr[ct][kk], acc[ct], 0, 0, 0);
        }

        const int orow0 = t * 16 + (lane >> 4) * 4;
        float dv[4];
#pragma unroll
        for (int r = 0; r < 4; ++r) {
            int rr = orow0 + r;
            dv[r] = SCALE ? ((rr < n) ? dis[rr] : 0.f) : 1.f;
        }
#pragma unroll
        for (int ct = 0; ct < 4; ++ct) {
            int colc = wave * 64 + ct * 16 + lrow;
#pragma unroll
            for (int r = 0; r < 4; ++r) {
                int rr = orow0 + r;
                if (rr < n) {
                    float v = fmaxf(acc[ct][r] + bias[ct], 0.f);
                    if (SCALE) v *= dv[r];
                    // slice-major [*/16][n][16]; 16 lanes -> 32B contiguous
                    out[(size_t)(colc >> 4) * ((size_t)n * 16) + (size_t)rr * 16 + (colc & 15)] =
                        __float2bfloat16(v);
                }
            }
        }
#pragma unroll
        for (int kk = 0; kk < KS; ++kk) aC[kk] = aN[kk];
    }
}

// ---------------- fused mean-pool + heads (slice-major input) ----------------
__global__ __launch_bounds__(THREADS) void pool_heads_kernel(
        const __hip_bfloat16* __restrict__ H, const int* __restrict__ goff,
        const float* __restrict__ Wmu, const float* __restrict__ bmu,
        const float* __restrict__ Wlv, const float* __restrict__ blv,
        float* __restrict__ out, int g_total, int n) {
    __shared__ float p[256];
    int g = blockIdx.x;
    int c = threadIdx.x;
    int s = goff[g], e = goff[g + 1];
    const __hip_bfloat16* Hs = H + (size_t)(c >> 4) * ((size_t)n * 16) + (c & 15);
    float acc = 0.f;
    for (int r = s; r < e; ++r) acc += __bfloat162float(Hs[(size_t)r * 16]);
    p[c] = acc / fmaxf((float)(e - s), 1.0f);
    __syncthreads();
    if (threadIdx.x < 128) {
        int cc = threadIdx.x & 63;
        bool is_mu = threadIdx.x < 64;
        const float* W = is_mu ? Wmu : Wlv;
        const float* bb = is_mu ? bmu : blv;
        float a = 0.f;
        for (int k = 0; k < 256; ++k) a = fmaf(p[k], W[k * 64 + cc], a);
        float* o = is_mu ? (out + (size_t)g * 64)
                         : (out + (size_t)g_total * 64 + (size_t)g * 64);
        o[cc] = a + bb[cc];
    }
}

extern "C" void kernel_launch(void* const* d_in, const int* in_sizes, int n_in,
                              void* d_out, int out_size, void* d_ws, size_t ws_size,
                              hipStream_t stream) {
    const float* x      = (const float*)d_in[0];
    const int*   eidx   = (const int*)d_in[1];
    const int*   batch  = (const int*)d_in[2];
    const float* W1  = (const float*)d_in[3];
    const float* b1  = (const float*)d_in[4];
    const float* W2  = (const float*)d_in[5];
    const float* b2  = (const float*)d_in[6];
    const float* W3  = (const float*)d_in[7];
    const float* b3  = (const float*)d_in[8];
    const float* Wmu = (const float*)d_in[9];
    const float* bmu = (const float*)d_in[10];
    const float* Wlv = (const float*)d_in[11];
    const float* blv = (const float*)d_in[12];
    float* out = (float*)d_out;

    const int N = in_sizes[0] / 10;
    const int E = in_sizes[1] / 2;
    const int G = out_size / 128;

    const int* src = eidx;       // edge_index[0]
    const int* dst = eidx + E;   // edge_index[1]

    // workspace carve-up (~118 MB)
    __hip_bfloat16* SA = (__hip_bfloat16*)d_ws;          // [N,256] bf16 ping (slice-major)
    __hip_bfloat16* SB = SA + (size_t)N * 256;           // [N,256] bf16 pong (slice-major)
    float* dis  = (float*)(SB + (size_t)N * 256);        // [N]
    __hip_bfloat16* W2T = (__hip_bfloat16*)(dis + N);    // [256][128]
    __hip_bfloat16* W3T = W2T + 256 * 128;               // [256][256]
    int* deg     = (int*)(W3T + 256 * 256);              // [N]
    int* row_ptr = deg + N;                              // [N+1]
    int* cursor  = row_ptr + N + 1;                      // [N]
    int* col     = cursor + N;                           // [E]
    int* goff    = col + E;                              // [G+1]

    const int ntiles = (N + 15) / 16;
    const int agg_grid = ((N + 127) / 128) * 8;

    // setup: deg=1, W transposes
    {
        int total = N + 128 * 256 + 256 * 256;
        setup_kernel<<<(total + THREADS - 1) / THREADS, THREADS, 0, stream>>>(
            deg, W2, W2T, W3, W3T, N);
    }
    // indegree hist + goff boundaries
    {
        int total = E + N;
        hist_bound_kernel<<<(total + THREADS - 1) / THREADS, THREADS, 0, stream>>>(
            dst, deg, E, batch, goff, N, G);
    }
    // scan: row_ptr (+cursor, +dis)
    scan_deg_kernel<<<1, 1024, 0, stream>>>(deg, row_ptr, cursor, dis, N);
    // XCD-pinned CSR fill (8 concurrent dst-slices)
    fill_csr_kernel<<<2048, THREADS, 0, stream>>>(src, dst, cursor, col, E, N);

    // layer 1: fused gather(x*dis) + 10->128 transform -> slice-major SA [8][N][16]
    layer1_kernel<<<(N + 15) / 16, THREADS, 0, stream>>>(
        x, row_ptr, col, dis, W1, b1, SA, N);

    // layer 2: sliced aggregate (8 slices) SA -> SB, MFMA 128->256 (*dis) -> SA [16][N][16]
    agg_slice16_kernel<0><<<agg_grid, THREADS, 0, stream>>>(SA, row_ptr, col, dis, SB, N);
    transform_mfma2_kernel<128, true><<<512, THREADS, 0, stream>>>(
        SB, W2T, b2, dis, SA, N, ntiles);

    // layer 3: sliced aggregate (16 slices, two 8-slice kernels) SA -> SB,
    //          MFMA 256->256 -> SA [16][N][16]
    agg_slice16_kernel<0><<<agg_grid, THREADS, 0, stream>>>(SA, row_ptr, col, dis, SB, N);
    agg_slice16_kernel<8><<<agg_grid, THREADS, 0, stream>>>(SA, row_ptr, col, dis, SB, N);
    transform_mfma2_kernel<256, false><<<512, THREADS, 0, stream>>>(
        SB, W3T, b3, dis, SA, N, ntiles);

    // fused mean pool + heads (slice-major input)
    pool_heads_kernel<<<G, THREADS, 0, stream>>>(SA, goff, Wmu, bmu, Wlv, blv, out, G, N);
}

// Round 13
// 548.840 us; speedup vs baseline: 1.1855x; 1.1673x over previous
//
#include <hip/hip_runtime.h>
#include <hip/hip_bf16.h>
#include <math.h>

// GraphEncoder: 3x GCNConv (relu) -> global_mean_pool -> two linear heads.
// N=100000, E=1600000, G=2048, feats 10->128->256->256->64(x2)
//
// Round-13 strategy:
//  - scan parallelized: round-12 profile showed the single-block scan_deg was
//    the #1 dispatch (100us, 0.18% occupancy) - hidden below the top-5 window
//    since round 2. Two-kernel hierarchy: 25-block partial sums + 25-block
//    final scan (thread-0 sums <=25 partials). Same per-element order ->
//    bit-identical row_ptr.
//  - XCD-pinned fill (round-12, confirmed: WRITE amplification gone),
//    slice-major activations + sliced agg (round-11/12) unchanged.

#define THREADS 256
#define SCAN_CHUNK 4096

typedef __attribute__((ext_vector_type(8))) short bf16x8;
typedef __attribute__((ext_vector_type(4))) float f32x4;
typedef __attribute__((ext_vector_type(4))) unsigned u32x4;

// ---------------- fused setup: deg=1, W2T, W3T ----------------
__global__ void setup_kernel(int* deg,
                             const float* __restrict__ W2, __hip_bfloat16* __restrict__ W2T,
                             const float* __restrict__ W3, __hip_bfloat16* __restrict__ W3T,
                             int n) {
    int i = blockIdx.x * blockDim.x + threadIdx.x;
    if (i < n) deg[i] = 1;                       // self-loop
    int r2 = i - n;
    if (r2 >= 0 && r2 < 128 * 256) {
        int k = r2 >> 8, c = r2 & 255;
        W2T[c * 128 + k] = __float2bfloat16(W2[r2]);
    }
    int r3 = i - n - 128 * 256;
    if (r3 >= 0 && r3 < 256 * 256) {
        int k = r3 >> 8, c = r3 & 255;
        W3T[c * 256 + k] = __float2bfloat16(W3[r3]);
    }
}

// ---------------- indegree hist + goff from sorted-batch boundaries ----------------
__global__ void hist_bound_kernel(const int* __restrict__ dst, int* deg, int e,
                                  const int* __restrict__ batch, int* goff,
                                  int n, int g) {
    int i = blockIdx.x * blockDim.x + threadIdx.x;
    if (i < e) {
        atomicAdd(&deg[dst[i]], 1);
    } else {
        int j = i - e;
        if (j < n) {
            int b = batch[j];
            if (j == 0) {
                for (int q = 0; q <= b; ++q) goff[q] = 0;
            } else {
                int bp = batch[j - 1];
                for (int q = bp + 1; q <= b; ++q) goff[q] = j;
            }
            if (j == n - 1) {
                for (int q = b + 1; q <= g; ++q) goff[q] = n;
            }
        }
    }
}

// ---------------- parallel scan, phase 1: per-chunk indegree sums ----------------
__global__ __launch_bounds__(1024) void scan_part_kernel(
        const int* __restrict__ deg, int* __restrict__ bsum, int n) {
    __shared__ int ws[16];
    const int lane = threadIdx.x & 63;
    const int wid = threadIdx.x >> 6;
    int i0 = blockIdx.x * SCAN_CHUNK + threadIdx.x * 4;
    int s = 0;
#pragma unroll
    for (int q = 0; q < 4; ++q) {
        int i = i0 + q;
        if (i < n) s += deg[i] - 1;
    }
#pragma unroll
    for (int off = 32; off > 0; off >>= 1) s += __shfl_down(s, off, 64);
    if (lane == 0) ws[wid] = s;
    __syncthreads();
    if (threadIdx.x == 0) {
        int t = 0;
        for (int w = 0; w < 16; ++w) t += ws[w];
        bsum[blockIdx.x] = t;
    }
}

// ---------------- parallel scan, phase 2: in-chunk scan + outputs ----------------
__global__ __launch_bounds__(1024) void scan_final_kernel(
        const int* __restrict__ deg, const int* __restrict__ bsum, int nb,
        int* __restrict__ row_ptr, int* __restrict__ cursor,
        float* __restrict__ dis, int n) {
    __shared__ int wsum[16];
    __shared__ int sbase;
    const int lane = threadIdx.x & 63;
    const int wid = threadIdx.x >> 6;
    if (threadIdx.x == 0) {
        int t = 0;
        for (int b = 0; b < blockIdx.x; ++b) t += bsum[b];
        sbase = t;
        if (blockIdx.x == 0) {
            int tot = 0;
            for (int b = 0; b < nb; ++b) tot += bsum[b];
            row_ptr[n] = tot;
        }
    }
    int i0 = blockIdx.x * SCAN_CHUNK + threadIdx.x * 4;
    int v[4];
#pragma unroll
    for (int q = 0; q < 4; ++q) {
        int i = i0 + q;
        v[q] = (i < n) ? (deg[i] - 1) : 0;
    }
    int tsum = v[0] + v[1] + v[2] + v[3];
    int incl = tsum;
#pragma unroll
    for (int off = 1; off < 64; off <<= 1) {
        int t = __shfl_up(incl, off, 64);
        if (lane >= off) incl += t;
    }
    if (lane == 63) wsum[wid] = incl;
    __syncthreads();
    int wbase = 0;
    for (int w = 0; w < wid; ++w) wbase += wsum[w];
    int pos = incl - tsum + wbase + sbase;
#pragma unroll
    for (int q = 0; q < 4; ++q) {
        int i = i0 + q;
        if (i < n) {
            row_ptr[i] = pos;
            cursor[i] = pos;
            dis[i] = rsqrtf((float)(v[q] + 1));
        }
        pos += v[q];
    }
}

// ---------------- XCD-pinned CSR fill: blockIdx&7 = dst-slice = XCD ----------
__global__ __launch_bounds__(THREADS) void fill_csr_kernel(
        const int* __restrict__ src, const int* __restrict__ dst,
        int* cursor, int* __restrict__ col, int e, int n) {
    const int slice = blockIdx.x & 7;
    const int sliceSize = (n + 7) / 8;
    const int lo = slice * sliceSize;
    const int hi = lo + sliceSize;
    const int tid = (blockIdx.x >> 3) * blockDim.x + threadIdx.x;
    const int nthr = (gridDim.x >> 3) * blockDim.x;
    for (int i = tid; i < e; i += nthr) {
        int d = dst[i];
        if (d >= lo && d < hi) {
            int pos = atomicAdd(&cursor[d], 1);
            col[pos] = src[i];
        }
    }
}

// ---------------- bf16 helpers ----------------
__device__ __forceinline__ void acc8(float* acc, uint4 v) {
    acc[0] += __uint_as_float(v.x << 16);
    acc[1] += __uint_as_float(v.x & 0xffff0000u);
    acc[2] += __uint_as_float(v.y << 16);
    acc[3] += __uint_as_float(v.y & 0xffff0000u);
    acc[4] += __uint_as_float(v.z << 16);
    acc[5] += __uint_as_float(v.z & 0xffff0000u);
    acc[6] += __uint_as_float(v.w << 16);
    acc[7] += __uint_as_float(v.w & 0xffff0000u);
}

__device__ __forceinline__ unsigned pack2(float a, float b) {
    unsigned short ua = __builtin_bit_cast(unsigned short, __float2bfloat16(a));
    unsigned short ub = __builtin_bit_cast(unsigned short, __float2bfloat16(b));
    return (unsigned)ua | ((unsigned)ub << 16);
}

// ---------------- fused layer 1: agg over 10-col x rows + 10->128 transform ----------------
__global__ __launch_bounds__(THREADS) void layer1_kernel(
        const float* __restrict__ x, const int* __restrict__ row_ptr,
        const int* __restrict__ col, const float* __restrict__ dis,
        const float* __restrict__ W1, const float* __restrict__ b1,
        __hip_bfloat16* __restrict__ out, int n) {
    __shared__ float h[16][12];
    __shared__ float w[10][128];
    __shared__ float bias[128];

    for (int idx = threadIdx.x; idx < 1280; idx += THREADS)
        w[idx >> 7][idx & 127] = W1[idx];
    if (threadIdx.x < 128) bias[threadIdx.x] = b1[threadIdx.x];

    const int node0 = blockIdx.x * 16;
    const int sub = threadIdx.x >> 4;
    const int lane = threadIdx.x & 15;
    const int node = node0 + sub;
    const bool act = (lane < 10) && (node < n);

    float acc = 0.f;
    float dn = 1.f;
    if (act) {
        dn = dis[node];
        acc = x[(size_t)node * 10 + lane] * dn;
        int s = row_ptr[node], e = row_ptr[node + 1];
        int p = s;
        for (; p + 8 <= e; p += 8) {
            int j[8];
#pragma unroll
            for (int q = 0; q < 8; ++q) j[q] = col[p + q];
            float v[8];
#pragma unroll
            for (int q = 0; q < 8; ++q) v[q] = x[(size_t)j[q] * 10 + lane] * dis[j[q]];
#pragma unroll
            for (int q = 0; q < 8; ++q) acc += v[q];
        }
        for (; p < e; ++p) {
            int j = col[p];
            acc += x[(size_t)j * 10 + lane] * dis[j];
        }
        acc *= dn;
    }
    if (lane < 12) h[sub][lane] = (lane < 10) ? acc : 0.f;
    __syncthreads();

    if (threadIdx.x < 128) {
        const int slice = threadIdx.x >> 4;   // 0..7
        const int r = threadIdx.x & 15;
        const int nodeB = node0 + r;
        if (nodeB < n) {
            float dnB = dis[nodeB];
            float hv[10];
#pragma unroll
            for (int k = 0; k < 10; ++k) hv[k] = h[r][k];
            unsigned rr[8];
#pragma unroll
            for (int cc = 0; cc < 16; cc += 2) {
                int c = slice * 16 + cc;
                float a0 = bias[c], a1 = bias[c + 1];
#pragma unroll
                for (int k = 0; k < 10; ++k) {
                    a0 = fmaf(hv[k], w[k][c], a0);
                    a1 = fmaf(hv[k], w[k][c + 1], a1);
                }
                rr[cc >> 1] = pack2(fmaxf(a0, 0.f) * dnB, fmaxf(a1, 0.f) * dnB);
            }
            uint4 res0 = make_uint4(rr[0], rr[1], rr[2], rr[3]);
            uint4 res1 = make_uint4(rr[4], rr[5], rr[6], rr[7]);
            size_t base = (size_t)slice * ((size_t)n * 2) + (size_t)nodeB * 2;
            reinterpret_cast<uint4*>(out)[base] = res0;
            reinterpret_cast<uint4*>(out)[base + 1] = res1;
        }
    }
}

// ---------------- XCD-sliced agg, 16-col slices (3.2MB, L2-resident) ----------
template <int SOFF>
__global__ __launch_bounds__(THREADS) void agg_slice16_kernel(
        const __hip_bfloat16* __restrict__ S, const int* __restrict__ row_ptr,
        const int* __restrict__ col, const float* __restrict__ dis,
        __hip_bfloat16* __restrict__ out, int n) {
    const int slice = (blockIdx.x & 7) + SOFF;
    const int grp = blockIdx.x >> 3;
    const int sub = threadIdx.x >> 1;
    const int lane = threadIdx.x & 1;
    const int node = grp * 128 + sub;
    if (node >= n) return;

    const uint4* S4 = reinterpret_cast<const uint4*>(S);
    const size_t sbase = (size_t)slice * ((size_t)n * 2);

    float acc[8];
#pragma unroll
    for (int q = 0; q < 8; ++q) acc[q] = 0.f;
    acc8(acc, S4[sbase + (size_t)node * 2 + lane]);   // self-loop term

    int s = row_ptr[node], e = row_ptr[node + 1];
    int p = s;
    for (; p + 8 <= e; p += 8) {
        int j[8];
#pragma unroll
        for (int q = 0; q < 8; ++q) j[q] = col[p + q];
        uint4 v[8];
#pragma unroll
        for (int q = 0; q < 8; ++q) v[q] = S4[sbase + (size_t)j[q] * 2 + lane];
#pragma unroll
        for (int q = 0; q < 8; ++q) acc8(acc, v[q]);
    }
    for (; p + 2 <= e; p += 2) {
        int j0 = col[p], j1 = col[p + 1];
        uint4 v0 = S4[sbase + (size_t)j0 * 2 + lane];
        uint4 v1 = S4[sbase + (size_t)j1 * 2 + lane];
        acc8(acc, v0); acc8(acc, v1);
    }
    for (; p < e; ++p) acc8(acc, S4[sbase + (size_t)col[p] * 2 + lane]);

    float d = dis[node];
    u32x4 o;
    o.x = pack2(acc[0] * d, acc[1] * d);
    o.y = pack2(acc[2] * d, acc[3] * d);
    o.z = pack2(acc[4] * d, acc[5] * d);
    o.w = pack2(acc[6] * d, acc[7] * d);
    __builtin_nontemporal_store(o,
        reinterpret_cast<u32x4*>(out) + sbase + (size_t)node * 2 + lane);
}

// ---------------- MFMA transform: slice-major A [K/16][n][16] -> slice-major out ----
template <int K, bool SCALE>
__global__ __launch_bounds__(THREADS) void transform_mfma2_kernel(
        const __hip_bfloat16* __restrict__ A, const __hip_bfloat16* __restrict__ WT,
        const float* __restrict__ b, const float* __restrict__ dis,
        __hip_bfloat16* __restrict__ out, int n, int ntiles) {
    constexpr int KS = K / 32;             // 4 (K=128) or 8 (K=256)
    const int wave = threadIdx.x >> 6;
    const int lane = threadIdx.x & 63;
    const int lrow = lane & 15;
    const int lk8  = (lane >> 4) * 8;      // k-element offset within a 32-k step

    const uint4* WT4 = reinterpret_cast<const uint4*>(WT);
    bf16x8 bfr[4][KS];
    float bias[4];
#pragma unroll
    for (int ct = 0; ct < 4; ++ct) {
        int colc = wave * 64 + ct * 16 + lrow;
        bias[ct] = b[colc];
#pragma unroll
        for (int kk = 0; kk < KS; ++kk)
            bfr[ct][kk] = __builtin_bit_cast(
                bf16x8, WT4[((size_t)colc * K + kk * 32 + lk8) >> 3]);
    }

    const uint4* A4 = reinterpret_cast<const uint4*>(A);
    auto loadA = [&](int t, uint4* av) {
        int row = t * 16 + lrow;
        if (row >= n) row = n - 1;
#pragma unroll
        for (int kk = 0; kk < KS; ++kk) {
            int c = kk * 32 + lk8;       // multiple of 8
            av[kk] = A4[(size_t)(c >> 4) * ((size_t)n * 2) + (size_t)row * 2 + ((c >> 3) & 1)];
        }
    };

    uint4 aC[KS], aN[KS];
    int t = blockIdx.x;
    if (t < ntiles) loadA(t, aC);

    for (; t < ntiles; t += gridDim.x) {
        int tn = t + gridDim.x;
        if (tn < ntiles) loadA(tn, aN);    // prefetch next tile

        f32x4 acc[4];
#pragma unroll
        for (int ct = 0; ct < 4; ++ct) acc[ct] = (f32x4){0.f, 0.f, 0.f, 0.f};
#pragma unroll
        for (int kk = 0; kk < KS; ++kk) {
            bf16x8 af = __builtin_bit_cast(bf16x8, aC[kk]);
#pragma unroll
            for (int ct = 0; ct < 4; ++ct)
                acc[ct] = __builtin_amdgcn_mfma_f32_16x16x32_bf16(af, bfr[ct][kk], acc[ct], 0, 0, 0);
        }

        const int orow0 = t * 16 + (lane >> 4) * 4;
        float dv[4];
#pragma unroll
        for (int r = 0; r < 4; ++r) {
            int rr = orow0 + r;
            dv[r] = SCALE ? ((rr < n) ? dis[rr] : 0.f) : 1.f;
        }
#pragma unroll
        for (int ct = 0; ct < 4; ++ct) {
            int colc = wave * 64 + ct * 16 + lrow;
#pragma unroll
            for (int r = 0; r < 4; ++r) {
                int rr = orow0 + r;
                if (rr < n) {
                    float v = fmaxf(acc[ct][r] + bias[ct], 0.f);
                    if (SCALE) v *= dv[r];
                    out[(size_t)(colc >> 4) * ((size_t)n * 16) + (size_t)rr * 16 + (colc & 15)] =
                        __float2bfloat16(v);
                }
            }
        }
#pragma unroll
        for (int kk = 0; kk < KS; ++kk) aC[kk] = aN[kk];
    }
}

// ---------------- fused mean-pool + heads (slice-major input) ----------------
__global__ __launch_bounds__(THREADS) void pool_heads_kernel(
        const __hip_bfloat16* __restrict__ H, const int* __restrict__ goff,
        const float* __restrict__ Wmu, const float* __restrict__ bmu,
        const float* __restrict__ Wlv, const float* __restrict__ blv,
        float* __restrict__ out, int g_total, int n) {
    __shared__ float p[256];
    int g = blockIdx.x;
    int c = threadIdx.x;
    int s = goff[g], e = goff[g + 1];
    const __hip_bfloat16* Hs = H + (size_t)(c >> 4) * ((size_t)n * 16) + (c & 15);
    float acc = 0.f;
    for (int r = s; r < e; ++r) acc += __bfloat162float(Hs[(size_t)r * 16]);
    p[c] = acc / fmaxf((float)(e - s), 1.0f);
    __syncthreads();
    if (threadIdx.x < 128) {
        int cc = threadIdx.x & 63;
        bool is_mu = threadIdx.x < 64;
        const float* W = is_mu ? Wmu : Wlv;
        const float* bb = is_mu ? bmu : blv;
        float a = 0.f;
        for (int k = 0; k < 256; ++k) a = fmaf(p[k], W[k * 64 + cc], a);
        float* o = is_mu ? (out + (size_t)g * 64)
                         : (out + (size_t)g_total * 64 + (size_t)g * 64);
        o[cc] = a + bb[cc];
    }
}

extern "C" void kernel_launch(void* const* d_in, const int* in_sizes, int n_in,
                              void* d_out, int out_size, void* d_ws, size_t ws_size,
                              hipStream_t stream) {
    const float* x      = (const float*)d_in[0];
    const int*   eidx   = (const int*)d_in[1];
    const int*   batch  = (const int*)d_in[2];
    const float* W1  = (const float*)d_in[3];
    const float* b1  = (const float*)d_in[4];
    const float* W2  = (const float*)d_in[5];
    const float* b2  = (const float*)d_in[6];
    const float* W3  = (const float*)d_in[7];
    const float* b3  = (const float*)d_in[8];
    const float* Wmu = (const float*)d_in[9];
    const float* bmu = (const float*)d_in[10];
    const float* Wlv = (const float*)d_in[11];
    const float* blv = (const float*)d_in[12];
    float* out = (float*)d_out;

    const int N = in_sizes[0] / 10;
    const int E = in_sizes[1] / 2;
    const int G = out_size / 128;

    const int* src = eidx;       // edge_index[0]
    const int* dst = eidx + E;   // edge_index[1]

    // workspace carve-up (~118 MB)
    __hip_bfloat16* SA = (__hip_bfloat16*)d_ws;          // [N,256] bf16 ping (slice-major)
    __hip_bfloat16* SB = SA + (size_t)N * 256;           // [N,256] bf16 pong (slice-major)
    float* dis  = (float*)(SB + (size_t)N * 256);        // [N]
    __hip_bfloat16* W2T = (__hip_bfloat16*)(dis + N);    // [256][128]
    __hip_bfloat16* W3T = W2T + 256 * 128;               // [256][256]
    int* deg     = (int*)(W3T + 256 * 256);              // [N]
    int* row_ptr = deg + N;                              // [N+1]
    int* cursor  = row_ptr + N + 1;                      // [N]
    int* col     = cursor + N;                           // [E]
    int* goff    = col + E;                              // [G+1]
    int* bsum    = goff + G + 1;                         // [nb]

    const int ntiles = (N + 15) / 16;
    const int agg_grid = ((N + 127) / 128) * 8;
    const int nb = (N + SCAN_CHUNK - 1) / SCAN_CHUNK;

    // setup: deg=1, W transposes
    {
        int total = N + 128 * 256 + 256 * 256;
        setup_kernel<<<(total + THREADS - 1) / THREADS, THREADS, 0, stream>>>(
            deg, W2, W2T, W3, W3T, N);
    }
    // indegree hist + goff boundaries
    {
        int total = E + N;
        hist_bound_kernel<<<(total + THREADS - 1) / THREADS, THREADS, 0, stream>>>(
            dst, deg, E, batch, goff, N, G);
    }
    // parallel scan: partials then final (row_ptr + cursor + dis)
    scan_part_kernel<<<nb, 1024, 0, stream>>>(deg, bsum, N);
    scan_final_kernel<<<nb, 1024, 0, stream>>>(deg, bsum, nb, row_ptr, cursor, dis, N);
    // XCD-pinned CSR fill (8 concurrent dst-slices)
    fill_csr_kernel<<<2048, THREADS, 0, stream>>>(src, dst, cursor, col, E, N);

    // layer 1: fused gather(x*dis) + 10->128 transform -> slice-major SA [8][N][16]
    layer1_kernel<<<(N + 15) / 16, THREADS, 0, stream>>>(
        x, row_ptr, col, dis, W1, b1, SA, N);

    // layer 2: sliced aggregate (8 slices) SA -> SB, MFMA 128->256 (*dis) -> SA [16][N][16]
    agg_slice16_kernel<0><<<agg_grid, THREADS, 0, stream>>>(SA, row_ptr, col, dis, SB, N);
    transform_mfma2_kernel<128, true><<<512, THREADS, 0, stream>>>(
        SB, W2T, b2, dis, SA, N, ntiles);

    // layer 3: sliced aggregate (16 slices, two 8-slice kernels) SA -> SB,
    //          MFMA 256->256 -> SA [16][N][16]
    agg_slice16_kernel<0><<<agg_grid, THREADS, 0, stream>>>(SA, row_ptr, col, dis, SB, N);
    agg_slice16_kernel<8><<<agg_grid, THREADS, 0, stream>>>(SA, row_ptr, col, dis, SB, N);
    transform_mfma2_kernel<256, false><<<512, THREADS, 0, stream>>>(
        SB, W3T, b3, dis, SA, N, ntiles);

    // fused mean pool + heads (slice-major input)
    pool_heads_kernel<<<G, THREADS, 0, stream>>>(SA, goff, Wmu, bmu, Wlv, blv, out, G, N);
}

// Round 14
// 484.178 us; speedup vs baseline: 1.3439x; 1.1335x over previous
//
#include <hip/hip_runtime.h>
#include <hip/hip_bf16.h>
#include <math.h>

// GraphEncoder: 3x GCNConv (relu) -> global_mean_pool -> two linear heads.
// N=100000, E=1600000, G=2048, feats 10->128->256->256->64(x2)
//
// Round-14: recombination of proven winners.
//  - agg: ROW-MAJOR (round-8). Round-13 proved sliced agg reduces HBM FETCH 5x
//    but delivers bytes SLOWER (5.15 vs 6.9 TB/s): aggs are latency-bound, and
//    32B/node granules expose more latency per byte than 512B rows. 237->176us.
//  - XCD-pinned fill (round-12): single-writer-XCD col lines. CONFIRMED.
//  - parallel scan (round-13): 100->10us. CONFIRMED.
//  - NEW: XCD-pinned deg histogram (same single-writer mechanism as fill).
//    goff boundaries moved into setup.

#define THREADS 256
#define SCAN_CHUNK 4096

typedef __attribute__((ext_vector_type(8))) short bf16x8;
typedef __attribute__((ext_vector_type(4))) float f32x4;

// ---------------- fused setup: deg=1, W2T, W3T, goff boundaries ----------------
__global__ void setup_kernel(int* deg,
                             const float* __restrict__ W2, __hip_bfloat16* __restrict__ W2T,
                             const float* __restrict__ W3, __hip_bfloat16* __restrict__ W3T,
                             const int* __restrict__ batch, int* goff,
                             int n, int g) {
    int i = blockIdx.x * blockDim.x + threadIdx.x;
    if (i < n) deg[i] = 1;                       // self-loop
    int r2 = i - n;
    if (r2 >= 0 && r2 < 128 * 256) {
        int k = r2 >> 8, c = r2 & 255;
        W2T[c * 128 + k] = __float2bfloat16(W2[r2]);
    }
    int r3 = i - n - 128 * 256;
    if (r3 >= 0 && r3 < 256 * 256) {
        int k = r3 >> 8, c = r3 & 255;
        W3T[c * 256 + k] = __float2bfloat16(W3[r3]);
    }
    int r4 = i - n - 128 * 256 - 256 * 256;
    if (r4 >= 0 && r4 < n) {
        int j = r4;
        int b = batch[j];
        if (j == 0) {
            for (int q = 0; q <= b; ++q) goff[q] = 0;
        } else {
            int bp = batch[j - 1];
            for (int q = bp + 1; q <= b; ++q) goff[q] = j;
        }
        if (j == n - 1) {
            for (int q = b + 1; q <= g; ++q) goff[q] = n;
        }
    }
}

// ---------------- XCD-pinned indegree histogram (blockIdx&7 = dst-slice) -------
// Single-owner XCD per deg line: no cross-XCD atomic coherence ping-pong.
__global__ __launch_bounds__(THREADS) void hist_deg_kernel(
        const int* __restrict__ dst, int* deg, int e, int n) {
    const int slice = blockIdx.x & 7;
    const int sliceSize = (n + 7) / 8;
    const int lo = slice * sliceSize;
    const int hi = lo + sliceSize;
    const int tid = (blockIdx.x >> 3) * blockDim.x + threadIdx.x;
    const int nthr = (gridDim.x >> 3) * blockDim.x;
    for (int i = tid; i < e; i += nthr) {
        int d = dst[i];
        if (d >= lo && d < hi) atomicAdd(&deg[d], 1);
    }
}

// ---------------- parallel scan, phase 1: per-chunk indegree sums ----------------
__global__ __launch_bounds__(1024) void scan_part_kernel(
        const int* __restrict__ deg, int* __restrict__ bsum, int n) {
    __shared__ int ws[16];
    const int lane = threadIdx.x & 63;
    const int wid = threadIdx.x >> 6;
    int i0 = blockIdx.x * SCAN_CHUNK + threadIdx.x * 4;
    int s = 0;
#pragma unroll
    for (int q = 0; q < 4; ++q) {
        int i = i0 + q;
        if (i < n) s += deg[i] - 1;
    }
#pragma unroll
    for (int off = 32; off > 0; off >>= 1) s += __shfl_down(s, off, 64);
    if (lane == 0) ws[wid] = s;
    __syncthreads();
    if (threadIdx.x == 0) {
        int t = 0;
        for (int w = 0; w < 16; ++w) t += ws[w];
        bsum[blockIdx.x] = t;
    }
}

// ---------------- parallel scan, phase 2: in-chunk scan + outputs ----------------
__global__ __launch_bounds__(1024) void scan_final_kernel(
        const int* __restrict__ deg, const int* __restrict__ bsum, int nb,
        int* __restrict__ row_ptr, int* __restrict__ cursor,
        float* __restrict__ dis, int n) {
    __shared__ int wsum[16];
    __shared__ int sbase;
    const int lane = threadIdx.x & 63;
    const int wid = threadIdx.x >> 6;
    if (threadIdx.x == 0) {
        int t = 0;
        for (int b = 0; b < blockIdx.x; ++b) t += bsum[b];
        sbase = t;
        if (blockIdx.x == 0) {
            int tot = 0;
            for (int b = 0; b < nb; ++b) tot += bsum[b];
            row_ptr[n] = tot;
        }
    }
    int i0 = blockIdx.x * SCAN_CHUNK + threadIdx.x * 4;
    int v[4];
#pragma unroll
    for (int q = 0; q < 4; ++q) {
        int i = i0 + q;
        v[q] = (i < n) ? (deg[i] - 1) : 0;
    }
    int tsum = v[0] + v[1] + v[2] + v[3];
    int incl = tsum;
#pragma unroll
    for (int off = 1; off < 64; off <<= 1) {
        int t = __shfl_up(incl, off, 64);
        if (lane >= off) incl += t;
    }
    if (lane == 63) wsum[wid] = incl;
    __syncthreads();
    int wbase = 0;
    for (int w = 0; w < wid; ++w) wbase += wsum[w];
    int pos = incl - tsum + wbase + sbase;
#pragma unroll
    for (int q = 0; q < 4; ++q) {
        int i = i0 + q;
        if (i < n) {
            row_ptr[i] = pos;
            cursor[i] = pos;
            dis[i] = rsqrtf((float)(v[q] + 1));
        }
        pos += v[q];
    }
}

// ---------------- XCD-pinned CSR fill: blockIdx&7 = dst-slice = XCD ----------
__global__ __launch_bounds__(THREADS) void fill_csr_kernel(
        const int* __restrict__ src, const int* __restrict__ dst,
        int* cursor, int* __restrict__ col, int e, int n) {
    const int slice = blockIdx.x & 7;
    const int sliceSize = (n + 7) / 8;
    const int lo = slice * sliceSize;
    const int hi = lo + sliceSize;
    const int tid = (blockIdx.x >> 3) * blockDim.x + threadIdx.x;
    const int nthr = (gridDim.x >> 3) * blockDim.x;
    for (int i = tid; i < e; i += nthr) {
        int d = dst[i];
        if (d >= lo && d < hi) {
            int pos = atomicAdd(&cursor[d], 1);
            col[pos] = src[i];
        }
    }
}

// ---------------- bf16 helpers ----------------
__device__ __forceinline__ void acc8(float* acc, uint4 v) {
    acc[0] += __uint_as_float(v.x << 16);
    acc[1] += __uint_as_float(v.x & 0xffff0000u);
    acc[2] += __uint_as_float(v.y << 16);
    acc[3] += __uint_as_float(v.y & 0xffff0000u);
    acc[4] += __uint_as_float(v.z << 16);
    acc[5] += __uint_as_float(v.z & 0xffff0000u);
    acc[6] += __uint_as_float(v.w << 16);
    acc[7] += __uint_as_float(v.w & 0xffff0000u);
}

__device__ __forceinline__ unsigned pack2(float a, float b) {
    unsigned short ua = __builtin_bit_cast(unsigned short, __float2bfloat16(a));
    unsigned short ub = __builtin_bit_cast(unsigned short, __float2bfloat16(b));
    return (unsigned)ua | ((unsigned)ub << 16);
}

// ---------------- fused layer 1: agg over 10-col x rows + 10->128 transform ----------------
// Row-major output [n][128].
__global__ __launch_bounds__(THREADS) void layer1_kernel(
        const float* __restrict__ x, const int* __restrict__ row_ptr,
        const int* __restrict__ col, const float* __restrict__ dis,
        const float* __restrict__ W1, const float* __restrict__ b1,
        __hip_bfloat16* __restrict__ out, int n) {
    __shared__ float h[16][12];
    __shared__ float w[10][128];
    __shared__ float bias[128];

    for (int idx = threadIdx.x; idx < 1280; idx += THREADS)
        w[idx >> 7][idx & 127] = W1[idx];
    if (threadIdx.x < 128) bias[threadIdx.x] = b1[threadIdx.x];

    const int node0 = blockIdx.x * 16;
    const int sub = threadIdx.x >> 4;
    const int lane = threadIdx.x & 15;
    const int node = node0 + sub;
    const bool act = (lane < 10) && (node < n);

    float acc = 0.f;
    float dn = 1.f;
    if (act) {
        dn = dis[node];
        acc = x[(size_t)node * 10 + lane] * dn;
        int s = row_ptr[node], e = row_ptr[node + 1];
        int p = s;
        for (; p + 8 <= e; p += 8) {
            int j[8];
#pragma unroll
            for (int q = 0; q < 8; ++q) j[q] = col[p + q];
            float v[8];
#pragma unroll
            for (int q = 0; q < 8; ++q) v[q] = x[(size_t)j[q] * 10 + lane] * dis[j[q]];
#pragma unroll
            for (int q = 0; q < 8; ++q) acc += v[q];
        }
        for (; p < e; ++p) {
            int j = col[p];
            acc += x[(size_t)j * 10 + lane] * dis[j];
        }
        acc *= dn;
    }
    if (lane < 12) h[sub][lane] = (lane < 10) ? acc : 0.f;
    __syncthreads();

    const int r = threadIdx.x >> 4;
    const int c0 = (threadIdx.x & 15) * 8;
    const int nodeB = node0 + r;
    if (nodeB < n) {
        float dnB = dis[nodeB];
        float hv[10];
#pragma unroll
        for (int k = 0; k < 10; ++k) hv[k] = h[r][k];
        uint4 res;
        unsigned rr[4];
#pragma unroll
        for (int cc = 0; cc < 8; cc += 2) {
            float a0 = bias[c0 + cc], a1 = bias[c0 + cc + 1];
#pragma unroll
            for (int k = 0; k < 10; ++k) {
                a0 = fmaf(hv[k], w[k][c0 + cc], a0);
                a1 = fmaf(hv[k], w[k][c0 + cc + 1], a1);
            }
            rr[cc >> 1] = pack2(fmaxf(a0, 0.f) * dnB, fmaxf(a1, 0.f) * dnB);
        }
        res.x = rr[0]; res.y = rr[1]; res.z = rr[2]; res.w = rr[3];
        reinterpret_cast<uint4*>(out)[((size_t)nodeB * 128 + c0) >> 3] = res;
    }
}

// ---------------- agg over COLS-col bf16 rows; L = COLS/8 lanes/node (row-major) ----
template <int COLS, int L>
__global__ __launch_bounds__(THREADS) void agg_bf16_kernel(
        const __hip_bfloat16* __restrict__ S, const int* __restrict__ row_ptr,
        const int* __restrict__ col, const float* __restrict__ dis,
        __hip_bfloat16* __restrict__ out, int n) {
    static_assert(L * 8 == COLS, "");
    constexpr int stride = COLS / 8;       // uint4 per row
    int node = blockIdx.x * (THREADS / L) + threadIdx.x / L;
    if (node >= n) return;
    int lane = threadIdx.x % L;
    const uint4* S4 = reinterpret_cast<const uint4*>(S);

    float acc[8];
#pragma unroll
    for (int q = 0; q < 8; ++q) acc[q] = 0.f;
    acc8(acc, S4[(size_t)node * stride + lane]);   // self-loop term

    int s = row_ptr[node], e = row_ptr[node + 1];
    int p = s;
    for (; p + 8 <= e; p += 8) {
        int j[8];
#pragma unroll
        for (int q = 0; q < 8; ++q) j[q] = col[p + q];
        uint4 v[8];
#pragma unroll
        for (int q = 0; q < 8; ++q) v[q] = S4[(size_t)j[q] * stride + lane];
#pragma unroll
        for (int q = 0; q < 8; ++q) acc8(acc, v[q]);
    }
    for (; p + 2 <= e; p += 2) {
        int j0 = col[p], j1 = col[p + 1];
        uint4 v0 = S4[(size_t)j0 * stride + lane];
        uint4 v1 = S4[(size_t)j1 * stride + lane];
        acc8(acc, v0); acc8(acc, v1);
    }
    for (; p < e; ++p) acc8(acc, S4[(size_t)col[p] * stride + lane]);

    float d = dis[node];
    uint4 o;
    o.x = pack2(acc[0] * d, acc[1] * d);
    o.y = pack2(acc[2] * d, acc[3] * d);
    o.z = pack2(acc[4] * d, acc[5] * d);
    o.w = pack2(acc[6] * d, acc[7] * d);
    reinterpret_cast<uint4*>(out)[(size_t)node * stride + lane] = o;
}

// ---------------- MFMA transform v2: bf16 [N,K] @ WT[256][K] -> bf16 [N,256] ----------------
template <int K, bool SCALE>
__global__ __launch_bounds__(THREADS) void transform_mfma2_kernel(
        const __hip_bfloat16* __restrict__ A, const __hip_bfloat16* __restrict__ WT,
        const float* __restrict__ b, const float* __restrict__ dis,
        __hip_bfloat16* __restrict__ out, int n, int ntiles) {
    constexpr int KS = K / 32;             // 4 (K=128) or 8 (K=256)
    const int wave = threadIdx.x >> 6;
    const int lane = threadIdx.x & 63;
    const int lrow = lane & 15;
    const int lk8  = (lane >> 4) * 8;      // k-element offset within a 32-k step

    const uint4* WT4 = reinterpret_cast<const uint4*>(WT);
    bf16x8 bfr[4][KS];
    float bias[4];
#pragma unroll
    for (int ct = 0; ct < 4; ++ct) {
        int colc = wave * 64 + ct * 16 + lrow;
        bias[ct] = b[colc];
#pragma unroll
        for (int kk = 0; kk < KS; ++kk)
            bfr[ct][kk] = __builtin_bit_cast(
                bf16x8, WT4[((size_t)colc * K + kk * 32 + lk8) >> 3]);
    }

    const uint4* A4 = reinterpret_cast<const uint4*>(A);
    auto loadA = [&](int t, uint4* av) {
        int row = t * 16 + lrow;
        if (row >= n) row = n - 1;
#pragma unroll
        for (int kk = 0; kk < KS; ++kk)
            av[kk] = A4[((size_t)row * K + kk * 32 + lk8) >> 3];
    };

    uint4 aC[KS], aN[KS];
    int t = blockIdx.x;
    if (t < ntiles) loadA(t, aC);

    for (; t < ntiles; t += gridDim.x) {
        int tn = t + gridDim.x;
        if (tn < ntiles) loadA(tn, aN);    // prefetch next tile

        f32x4 acc[4];
#pragma unroll
        for (int ct = 0; ct < 4; ++ct) acc[ct] = (f32x4){0.f, 0.f, 0.f, 0.f};
#pragma unroll
        for (int kk = 0; kk < KS; ++kk) {
            bf16x8 af = __builtin_bit_cast(bf16x8, aC[kk]);
#pragma unroll
            for (int ct = 0; ct < 4; ++ct)
                acc[ct] = __builtin_amdgcn_mfma_f32_16x16x32_bf16(af, bfr[ct][kk], acc[ct], 0, 0, 0);
        }

        const int orow0 = t * 16 + (lane >> 4) * 4;
        float dv[4];
#pragma unroll
        for (int r = 0; r < 4; ++r) {
            int rr = orow0 + r;
            dv[r] = SCALE ? ((rr < n) ? dis[rr] : 0.f) : 1.f;
        }
#pragma unroll
        for (int ct = 0; ct < 4; ++ct) {
            int colc = wave * 64 + ct * 16 + lrow;
#pragma unroll
            for (int r = 0; r < 4; ++r) {
                int rr = orow0 + r;
                if (rr < n) {
                    float v = fmaxf(acc[ct][r] + bias[ct], 0.f);
                    if (SCALE) v *= dv[r];
                    out[(size_t)rr * 256 + colc] = __float2bfloat16(v);
                }
            }
        }
#pragma unroll
        for (int kk = 0; kk < KS; ++kk) aC[kk] = aN[kk];
    }
}

// ---------------- fused mean-pool + heads (row-major input) ----------------
__global__ __launch_bounds__(THREADS) void pool_heads_kernel(
        const __hip_bfloat16* __restrict__ H, const int* __restrict__ goff,
        const float* __restrict__ Wmu, const float* __restrict__ bmu,
        const float* __restrict__ Wlv, const float* __restrict__ blv,
        float* __restrict__ out, int g_total) {
    __shared__ float p[256];
    int g = blockIdx.x;
    int c = threadIdx.x;
    int s = goff[g], e = goff[g + 1];
    float acc = 0.f;
    for (int r = s; r < e; ++r) acc += __bfloat162float(H[(size_t)r * 256 + c]);
    p[c] = acc / fmaxf((float)(e - s), 1.0f);
    __syncthreads();
    if (threadIdx.x < 128) {
        int cc = threadIdx.x & 63;
        bool is_mu = threadIdx.x < 64;
        const float* W = is_mu ? Wmu : Wlv;
        const float* bb = is_mu ? bmu : blv;
        float a = 0.f;
        for (int k = 0; k < 256; ++k) a = fmaf(p[k], W[k * 64 + cc], a);
        float* o = is_mu ? (out + (size_t)g * 64)
                         : (out + (size_t)g_total * 64 + (size_t)g * 64);
        o[cc] = a + bb[cc];
    }
}

extern "C" void kernel_launch(void* const* d_in, const int* in_sizes, int n_in,
                              void* d_out, int out_size, void* d_ws, size_t ws_size,
                              hipStream_t stream) {
    const float* x      = (const float*)d_in[0];
    const int*   eidx   = (const int*)d_in[1];
    const int*   batch  = (const int*)d_in[2];
    const float* W1  = (const float*)d_in[3];
    const float* b1  = (const float*)d_in[4];
    const float* W2  = (const float*)d_in[5];
    const float* b2  = (const float*)d_in[6];
    const float* W3  = (const float*)d_in[7];
    const float* b3  = (const float*)d_in[8];
    const float* Wmu = (const float*)d_in[9];
    const float* bmu = (const float*)d_in[10];
    const float* Wlv = (const float*)d_in[11];
    const float* blv = (const float*)d_in[12];
    float* out = (float*)d_out;

    const int N = in_sizes[0] / 10;
    const int E = in_sizes[1] / 2;
    const int G = out_size / 128;

    const int* src = eidx;       // edge_index[0]
    const int* dst = eidx + E;   // edge_index[1]

    // workspace carve-up (~118 MB)
    __hip_bfloat16* SA = (__hip_bfloat16*)d_ws;          // [N,256] bf16 ping (row-major)
    __hip_bfloat16* SB = SA + (size_t)N * 256;           // [N,256] bf16 pong (row-major)
    float* dis  = (float*)(SB + (size_t)N * 256);        // [N]
    __hip_bfloat16* W2T = (__hip_bfloat16*)(dis + N);    // [256][128]
    __hip_bfloat16* W3T = W2T + 256 * 128;               // [256][256]
    int* deg     = (int*)(W3T + 256 * 256);              // [N]
    int* row_ptr = deg + N;                              // [N+1]
    int* cursor  = row_ptr + N + 1;                      // [N]
    int* col     = cursor + N;                           // [E]
    int* goff    = col + E;                              // [G+1]
    int* bsum    = goff + G + 1;                         // [nb]

    const int ntiles = (N + 15) / 16;
    const int nb = (N + SCAN_CHUNK - 1) / SCAN_CHUNK;

    // setup: deg=1, W transposes, goff boundaries
    {
        int total = 2 * N + 128 * 256 + 256 * 256;
        setup_kernel<<<(total + THREADS - 1) / THREADS, THREADS, 0, stream>>>(
            deg, W2, W2T, W3, W3T, batch, goff, N, G);
    }
    // XCD-pinned indegree histogram
    hist_deg_kernel<<<2048, THREADS, 0, stream>>>(dst, deg, E, N);
    // parallel scan: partials then final (row_ptr + cursor + dis)
    scan_part_kernel<<<nb, 1024, 0, stream>>>(deg, bsum, N);
    scan_final_kernel<<<nb, 1024, 0, stream>>>(deg, bsum, nb, row_ptr, cursor, dis, N);
    // XCD-pinned CSR fill
    fill_csr_kernel<<<2048, THREADS, 0, stream>>>(src, dst, cursor, col, E, N);

    // layer 1: fused gather(x*dis) + 10->128 transform -> row-major SA [N,128]
    layer1_kernel<<<(N + 15) / 16, THREADS, 0, stream>>>(
        x, row_ptr, col, dis, W1, b1, SA, N);

    // layer 2: aggregate S1 (128 bf16 cols) then MFMA transform 128->256 (*dis)
    agg_bf16_kernel<128, 16><<<(N + 15) / 16, THREADS, 0, stream>>>(SA, row_ptr, col, dis, SB, N);
    transform_mfma2_kernel<128, true><<<512, THREADS, 0, stream>>>(SB, W2T, b2, dis, SA, N, ntiles);

    // layer 3: aggregate S2 (256 bf16 cols) then MFMA transform 256->256
    agg_bf16_kernel<256, 32><<<(N + 7) / 8, THREADS, 0, stream>>>(SA, row_ptr, col, dis, SB, N);
    transform_mfma2_kernel<256, false><<<512, THREADS, 0, stream>>>(SB, W3T, b3, dis, SA, N, ntiles);

    // fused mean pool + heads
    pool_heads_kernel<<<G, THREADS, 0, stream>>>(SA, goff, Wmu, bmu, Wlv, blv, out, G);
}

// Round 15
// 477.720 us; speedup vs baseline: 1.3620x; 1.0135x over previous
//
#include <hip/hip_runtime.h>
#include <hip/hip_bf16.h>
#include <math.h>

// GraphEncoder: 3x GCNConv (relu) -> global_mean_pool -> two linear heads.
// N=100000, E=1600000, G=2048, feats 10->128->256->256->64(x2)
//
// Round-15: request-count attack. Round-14 counters established a chip-wide
// ~0.43 G vector-memory-requests/us ceiling (agg256 51.2M req/118us, agg128
// 25.6M/58us - identical rate). Aggs are AT that floor (persistence/slicing/
// MLP all probed). The other kernels were request-wasteful:
//  - pool_heads: scalar 2B bf16 loads (25.6M req) -> uint4 (3.2M req)
//  - hist/fill: scalar 4B edge reads -> uint4 (4 edges/request)
//  - layer1: 16M scalar 4B x-gathers -> xd[n][16] bf16 pre-pack (in
//    scan_final) + 2-lane uint4 gather (3.4M req) + in-LDS transform
// Aggs/transforms/scan/XCD-pinning unchanged (round-14 proven set).

#define THREADS 256
#define SCAN_CHUNK 4096

typedef __attribute__((ext_vector_type(8))) short bf16x8;
typedef __attribute__((ext_vector_type(4))) float f32x4;

// ---------------- fused setup: deg=1, W2T, W3T, goff boundaries ----------------
__global__ void setup_kernel(int* deg,
                             const float* __restrict__ W2, __hip_bfloat16* __restrict__ W2T,
                             const float* __restrict__ W3, __hip_bfloat16* __restrict__ W3T,
                             const int* __restrict__ batch, int* goff,
                             int n, int g) {
    int i = blockIdx.x * blockDim.x + threadIdx.x;
    if (i < n) deg[i] = 1;                       // self-loop
    int r2 = i - n;
    if (r2 >= 0 && r2 < 128 * 256) {
        int k = r2 >> 8, c = r2 & 255;
        W2T[c * 128 + k] = __float2bfloat16(W2[r2]);
    }
    int r3 = i - n - 128 * 256;
    if (r3 >= 0 && r3 < 256 * 256) {
        int k = r3 >> 8, c = r3 & 255;
        W3T[c * 256 + k] = __float2bfloat16(W3[r3]);
    }
    int r4 = i - n - 128 * 256 - 256 * 256;
    if (r4 >= 0 && r4 < n) {
        int j = r4;
        int b = batch[j];
        if (j == 0) {
            for (int q = 0; q <= b; ++q) goff[q] = 0;
        } else {
            int bp = batch[j - 1];
            for (int q = bp + 1; q <= b; ++q) goff[q] = j;
        }
        if (j == n - 1) {
            for (int q = b + 1; q <= g; ++q) goff[q] = n;
        }
    }
}

// ---------------- XCD-pinned indegree histogram, uint4 edge reads -------------
__global__ __launch_bounds__(THREADS) void hist_deg_kernel(
        const int* __restrict__ dst, int* deg, int e, int n) {
    const int slice = blockIdx.x & 7;
    const int sliceSize = (n + 7) / 8;
    const int lo = slice * sliceSize;
    const int hi = lo + sliceSize;
    const int tid = (blockIdx.x >> 3) * blockDim.x + threadIdx.x;
    const int nthr = (gridDim.x >> 3) * blockDim.x;
    const int e4 = e >> 2;
    const uint4* dst4 = reinterpret_cast<const uint4*>(dst);
    for (int i = tid; i < e4; i += nthr) {
        uint4 dv = dst4[i];
        int dd[4] = {(int)dv.x, (int)dv.y, (int)dv.z, (int)dv.w};
#pragma unroll
        for (int q = 0; q < 4; ++q)
            if (dd[q] >= lo && dd[q] < hi) atomicAdd(&deg[dd[q]], 1);
    }
    for (int i = (e & ~3) + tid; i < e; i += nthr) {
        int d = dst[i];
        if (d >= lo && d < hi) atomicAdd(&deg[d], 1);
    }
}

// ---------------- parallel scan, phase 1: per-chunk indegree sums ----------------
__global__ __launch_bounds__(1024) void scan_part_kernel(
        const int* __restrict__ deg, int* __restrict__ bsum, int n) {
    __shared__ int ws[16];
    const int lane = threadIdx.x & 63;
    const int wid = threadIdx.x >> 6;
    int i0 = blockIdx.x * SCAN_CHUNK + threadIdx.x * 4;
    int s = 0;
#pragma unroll
    for (int q = 0; q < 4; ++q) {
        int i = i0 + q;
        if (i < n) s += deg[i] - 1;
    }
#pragma unroll
    for (int off = 32; off > 0; off >>= 1) s += __shfl_down(s, off, 64);
    if (lane == 0) ws[wid] = s;
    __syncthreads();
    if (threadIdx.x == 0) {
        int t = 0;
        for (int w = 0; w < 16; ++w) t += ws[w];
        bsum[blockIdx.x] = t;
    }
}

__device__ __forceinline__ unsigned pack2(float a, float b) {
    unsigned short ua = __builtin_bit_cast(unsigned short, __float2bfloat16(a));
    unsigned short ub = __builtin_bit_cast(unsigned short, __float2bfloat16(b));
    return (unsigned)ua | ((unsigned)ub << 16);
}

// ---------------- parallel scan, phase 2: scan + row_ptr/cursor/dis + xd pack ----
// xd[i][0..15] = bf16(x[i][k] * dis[i]) (k<10), zero pad to 16.
__global__ __launch_bounds__(1024) void scan_final_kernel(
        const int* __restrict__ deg, const int* __restrict__ bsum, int nb,
        int* __restrict__ row_ptr, int* __restrict__ cursor,
        float* __restrict__ dis, const float* __restrict__ x,
        __hip_bfloat16* __restrict__ xd, int n) {
    __shared__ int wsum[16];
    __shared__ int sbase;
    const int lane = threadIdx.x & 63;
    const int wid = threadIdx.x >> 6;
    if (threadIdx.x == 0) {
        int t = 0;
        for (int b = 0; b < blockIdx.x; ++b) t += bsum[b];
        sbase = t;
        if (blockIdx.x == 0) {
            int tot = 0;
            for (int b = 0; b < nb; ++b) tot += bsum[b];
            row_ptr[n] = tot;
        }
    }
    int i0 = blockIdx.x * SCAN_CHUNK + threadIdx.x * 4;
    int v[4];
#pragma unroll
    for (int q = 0; q < 4; ++q) {
        int i = i0 + q;
        v[q] = (i < n) ? (deg[i] - 1) : 0;
    }
    int tsum = v[0] + v[1] + v[2] + v[3];
    int incl = tsum;
#pragma unroll
    for (int off = 1; off < 64; off <<= 1) {
        int t = __shfl_up(incl, off, 64);
        if (lane >= off) incl += t;
    }
    if (lane == 63) wsum[wid] = incl;
    __syncthreads();
    int wbase = 0;
    for (int w = 0; w < wid; ++w) wbase += wsum[w];
    int pos = incl - tsum + wbase + sbase;
    uint4* xd4 = reinterpret_cast<uint4*>(xd);
#pragma unroll
    for (int q = 0; q < 4; ++q) {
        int i = i0 + q;
        if (i < n) {
            row_ptr[i] = pos;
            cursor[i] = pos;
            float dv = rsqrtf((float)(v[q] + 1));
            dis[i] = dv;
            unsigned ow[8];
#pragma unroll
            for (int k = 0; k < 5; ++k)
                ow[k] = pack2(x[(size_t)i * 10 + 2 * k] * dv,
                              x[(size_t)i * 10 + 2 * k + 1] * dv);
            ow[5] = 0; ow[6] = 0; ow[7] = 0;
            xd4[(size_t)i * 2]     = make_uint4(ow[0], ow[1], ow[2], ow[3]);
            xd4[(size_t)i * 2 + 1] = make_uint4(ow[4], ow[5], ow[6], ow[7]);
        }
        pos += v[q];
    }
}

// ---------------- XCD-pinned CSR fill, uint4 edge reads ----------------
__global__ __launch_bounds__(THREADS) void fill_csr_kernel(
        const int* __restrict__ src, const int* __restrict__ dst,
        int* cursor, int* __restrict__ col, int e, int n) {
    const int slice = blockIdx.x & 7;
    const int sliceSize = (n + 7) / 8;
    const int lo = slice * sliceSize;
    const int hi = lo + sliceSize;
    const int tid = (blockIdx.x >> 3) * blockDim.x + threadIdx.x;
    const int nthr = (gridDim.x >> 3) * blockDim.x;
    const int e4 = e >> 2;
    const uint4* dst4 = reinterpret_cast<const uint4*>(dst);
    const uint4* src4 = reinterpret_cast<const uint4*>(src);
    for (int i = tid; i < e4; i += nthr) {
        uint4 dv = dst4[i];
        int dd[4] = {(int)dv.x, (int)dv.y, (int)dv.z, (int)dv.w};
        bool any = false;
#pragma unroll
        for (int q = 0; q < 4; ++q) any |= (dd[q] >= lo && dd[q] < hi);
        if (!any) continue;
        uint4 sv = src4[i];
        int ss[4] = {(int)sv.x, (int)sv.y, (int)sv.z, (int)sv.w};
#pragma unroll
        for (int q = 0; q < 4; ++q) {
            if (dd[q] >= lo && dd[q] < hi) {
                int pos = atomicAdd(&cursor[dd[q]], 1);
                col[pos] = ss[q];
            }
        }
    }
    for (int i = (e & ~3) + tid; i < e; i += nthr) {
        int d = dst[i];
        if (d >= lo && d < hi) {
            int pos = atomicAdd(&cursor[d], 1);
            col[pos] = src[i];
        }
    }
}

// ---------------- bf16 helpers ----------------
__device__ __forceinline__ void acc8(float* acc, uint4 v) {
    acc[0] += __uint_as_float(v.x << 16);
    acc[1] += __uint_as_float(v.x & 0xffff0000u);
    acc[2] += __uint_as_float(v.y << 16);
    acc[3] += __uint_as_float(v.y & 0xffff0000u);
    acc[4] += __uint_as_float(v.z << 16);
    acc[5] += __uint_as_float(v.z & 0xffff0000u);
    acc[6] += __uint_as_float(v.w << 16);
    acc[7] += __uint_as_float(v.w & 0xffff0000u);
}

// ---------------- fused layer 1: 2-lane uint4 xd gather + 10->128 transform ----
// Block = 128 nodes. Phase A: 2 lanes/node gather xd rows (uint4), h -> LDS f32.
// Phase B: thread (node, half) computes 64 cols in 8-col steps, uint4 stores.
__global__ __launch_bounds__(THREADS) void layer1_kernel(
        const __hip_bfloat16* __restrict__ xd, const int* __restrict__ row_ptr,
        const int* __restrict__ col, const float* __restrict__ dis,
        const float* __restrict__ W1, const float* __restrict__ b1,
        __hip_bfloat16* __restrict__ out, int n) {
    __shared__ float h[128][12];
    __shared__ float w[10][128];
    __shared__ float bias[128];

    for (int idx = threadIdx.x; idx < 1280; idx += THREADS)
        w[idx >> 7][idx & 127] = W1[idx];
    if (threadIdx.x < 128) bias[threadIdx.x] = b1[threadIdx.x];

    const int node0 = blockIdx.x * 128;
    const int nl = threadIdx.x >> 1;
    const int lane = threadIdx.x & 1;
    const int node = node0 + nl;
    const uint4* S4 = reinterpret_cast<const uint4*>(xd);

    if (node < n) {
        float acc[8];
#pragma unroll
        for (int q = 0; q < 8; ++q) acc[q] = 0.f;
        acc8(acc, S4[(size_t)node * 2 + lane]);   // self (xd = x*dis)

        int s = row_ptr[node], e = row_ptr[node + 1];
        int p = s;
        for (; p + 8 <= e; p += 8) {
            int j[8];
#pragma unroll
            for (int q = 0; q < 8; ++q) j[q] = col[p + q];
            uint4 v[8];
#pragma unroll
            for (int q = 0; q < 8; ++q) v[q] = S4[(size_t)j[q] * 2 + lane];
#pragma unroll
            for (int q = 0; q < 8; ++q) acc8(acc, v[q]);
        }
        for (; p < e; ++p) acc8(acc, S4[(size_t)col[p] * 2 + lane]);

        float dn = dis[node];
        if (lane == 0) {
#pragma unroll
            for (int q = 0; q < 8; ++q) h[nl][q] = acc[q] * dn;
        } else {
            h[nl][8] = acc[0] * dn;
            h[nl][9] = acc[1] * dn;
        }
    }
    __syncthreads();

    const int half = threadIdx.x & 1;
    const int nodeB = node0 + (threadIdx.x >> 1);
    if (nodeB < n) {
        float dnB = dis[nodeB];
        float hv[10];
#pragma unroll
        for (int k = 0; k < 10; ++k) hv[k] = h[threadIdx.x >> 1][k];
#pragma unroll
        for (int step = 0; step < 8; ++step) {
            int c0 = half * 64 + step * 8;
            unsigned rr[4];
#pragma unroll
            for (int cc = 0; cc < 8; cc += 2) {
                float a0 = bias[c0 + cc], a1 = bias[c0 + cc + 1];
#pragma unroll
                for (int k = 0; k < 10; ++k) {
                    a0 = fmaf(hv[k], w[k][c0 + cc], a0);
                    a1 = fmaf(hv[k], w[k][c0 + cc + 1], a1);
                }
                rr[cc >> 1] = pack2(fmaxf(a0, 0.f) * dnB, fmaxf(a1, 0.f) * dnB);
            }
            reinterpret_cast<uint4*>(out)[((size_t)nodeB * 128 + c0) >> 3] =
                make_uint4(rr[0], rr[1], rr[2], rr[3]);
        }
    }
}

// ---------------- agg over COLS-col bf16 rows; L = COLS/8 lanes/node (row-major) ----
template <int COLS, int L>
__global__ __launch_bounds__(THREADS) void agg_bf16_kernel(
        const __hip_bfloat16* __restrict__ S, const int* __restrict__ row_ptr,
        const int* __restrict__ col, const float* __restrict__ dis,
        __hip_bfloat16* __restrict__ out, int n) {
    static_assert(L * 8 == COLS, "");
    constexpr int stride = COLS / 8;       // uint4 per row
    int node = blockIdx.x * (THREADS / L) + threadIdx.x / L;
    if (node >= n) return;
    int lane = threadIdx.x % L;
    const uint4* S4 = reinterpret_cast<const uint4*>(S);

    float acc[8];
#pragma unroll
    for (int q = 0; q < 8; ++q) acc[q] = 0.f;
    acc8(acc, S4[(size_t)node * stride + lane]);   // self-loop term

    int s = row_ptr[node], e = row_ptr[node + 1];
    int p = s;
    for (; p + 8 <= e; p += 8) {
        int j[8];
#pragma unroll
        for (int q = 0; q < 8; ++q) j[q] = col[p + q];
        uint4 v[8];
#pragma unroll
        for (int q = 0; q < 8; ++q) v[q] = S4[(size_t)j[q] * stride + lane];
#pragma unroll
        for (int q = 0; q < 8; ++q) acc8(acc, v[q]);
    }
    for (; p + 2 <= e; p += 2) {
        int j0 = col[p], j1 = col[p + 1];
        uint4 v0 = S4[(size_t)j0 * stride + lane];
        uint4 v1 = S4[(size_t)j1 * stride + lane];
        acc8(acc, v0); acc8(acc, v1);
    }
    for (; p < e; ++p) acc8(acc, S4[(size_t)col[p] * stride + lane]);

    float d = dis[node];
    uint4 o;
    o.x = pack2(acc[0] * d, acc[1] * d);
    o.y = pack2(acc[2] * d, acc[3] * d);
    o.z = pack2(acc[4] * d, acc[5] * d);
    o.w = pack2(acc[6] * d, acc[7] * d);
    reinterpret_cast<uint4*>(out)[(size_t)node * stride + lane] = o;
}

// ---------------- MFMA transform v2: bf16 [N,K] @ WT[256][K] -> bf16 [N,256] ----------------
template <int K, bool SCALE>
__global__ __launch_bounds__(THREADS) void transform_mfma2_kernel(
        const __hip_bfloat16* __restrict__ A, const __hip_bfloat16* __restrict__ WT,
        const float* __restrict__ b, const float* __restrict__ dis,
        __hip_bfloat16* __restrict__ out, int n, int ntiles) {
    constexpr int KS = K / 32;             // 4 (K=128) or 8 (K=256)
    const int wave = threadIdx.x >> 6;
    const int lane = threadIdx.x & 63;
    const int lrow = lane & 15;
    const int lk8  = (lane >> 4) * 8;      // k-element offset within a 32-k step

    const uint4* WT4 = reinterpret_cast<const uint4*>(WT);
    bf16x8 bfr[4][KS];
    float bias[4];
#pragma unroll
    for (int ct = 0; ct < 4; ++ct) {
        int colc = wave * 64 + ct * 16 + lrow;
        bias[ct] = b[colc];
#pragma unroll
        for (int kk = 0; kk < KS; ++kk)
            bfr[ct][kk] = __builtin_bit_cast(
                bf16x8, WT4[((size_t)colc * K + kk * 32 + lk8) >> 3]);
    }

    const uint4* A4 = reinterpret_cast<const uint4*>(A);
    auto loadA = [&](int t, uint4* av) {
        int row = t * 16 + lrow;
        if (row >= n) row = n - 1;
#pragma unroll
        for (int kk = 0; kk < KS; ++kk)
            av[kk] = A4[((size_t)row * K + kk * 32 + lk8) >> 3];
    };

    uint4 aC[KS], aN[KS];
    int t = blockIdx.x;
    if (t < ntiles) loadA(t, aC);

    for (; t < ntiles; t += gridDim.x) {
        int tn = t + gridDim.x;
        if (tn < ntiles) loadA(tn, aN);    // prefetch next tile

        f32x4 acc[4];
#pragma unroll
        for (int ct = 0; ct < 4; ++ct) acc[ct] = (f32x4){0.f, 0.f, 0.f, 0.f};
#pragma unroll
        for (int kk = 0; kk < KS; ++kk) {
            bf16x8 af = __builtin_bit_cast(bf16x8, aC[kk]);
#pragma unroll
            for (int ct = 0; ct < 4; ++ct)
                acc[ct] = __builtin_amdgcn_mfma_f32_16x16x32_bf16(af, bfr[ct][kk], acc[ct], 0, 0, 0);
        }

        const int orow0 = t * 16 + (lane >> 4) * 4;
        float dv[4];
#pragma unroll
        for (int r = 0; r < 4; ++r) {
            int rr = orow0 + r;
            dv[r] = SCALE ? ((rr < n) ? dis[rr] : 0.f) : 1.f;
        }
#pragma unroll
        for (int ct = 0; ct < 4; ++ct) {
            int colc = wave * 64 + ct * 16 + lrow;
#pragma unroll
            for (int r = 0; r < 4; ++r) {
                int rr = orow0 + r;
                if (rr < n) {
                    float v = fmaxf(acc[ct][r] + bias[ct], 0.f);
                    if (SCALE) v *= dv[r];
                    out[(size_t)rr * 256 + colc] = __float2bfloat16(v);
                }
            }
        }
#pragma unroll
        for (int kk = 0; kk < KS; ++kk) aC[kk] = aN[kk];
    }
}

// ---------------- fused mean-pool + heads, uint4 H reads ----------------
// 8 row-groups x 32 lanes; each lane accumulates 8 cols via uint4; LDS reduce.
__global__ __launch_bounds__(THREADS) void pool_heads_kernel(
        const __hip_bfloat16* __restrict__ H, const int* __restrict__ goff,
        const float* __restrict__ Wmu, const float* __restrict__ bmu,
        const float* __restrict__ Wlv, const float* __restrict__ blv,
        float* __restrict__ out, int g_total) {
    __shared__ float part[8][256];
    __shared__ float p[256];
    int g = blockIdx.x;
    int s = goff[g], e = goff[g + 1];
    int rgrp = threadIdx.x >> 5;
    int lane = threadIdx.x & 31;
    const uint4* H4 = reinterpret_cast<const uint4*>(H);

    float acc[8];
#pragma unroll
    for (int q = 0; q < 8; ++q) acc[q] = 0.f;
    for (int r = s + rgrp; r < e; r += 8)
        acc8(acc, H4[(size_t)r * 32 + lane]);
#pragma unroll
    for (int q = 0; q < 8; ++q) part[rgrp][lane * 8 + q] = acc[q];
    __syncthreads();

    int c = threadIdx.x;
    float t = 0.f;
#pragma unroll
    for (int gq = 0; gq < 8; ++gq) t += part[gq][c];
    p[c] = t / fmaxf((float)(e - s), 1.0f);
    __syncthreads();

    if (threadIdx.x < 128) {
        int cc = threadIdx.x & 63;
        bool is_mu = threadIdx.x < 64;
        const float* W = is_mu ? Wmu : Wlv;
        const float* bb = is_mu ? bmu : blv;
        float a = 0.f;
        for (int k = 0; k < 256; ++k) a = fmaf(p[k], W[k * 64 + cc], a);
        float* o = is_mu ? (out + (size_t)g * 64)
                         : (out + (size_t)g_total * 64 + (size_t)g * 64);
        o[cc] = a + bb[cc];
    }
}

extern "C" void kernel_launch(void* const* d_in, const int* in_sizes, int n_in,
                              void* d_out, int out_size, void* d_ws, size_t ws_size,
                              hipStream_t stream) {
    const float* x      = (const float*)d_in[0];
    const int*   eidx   = (const int*)d_in[1];
    const int*   batch  = (const int*)d_in[2];
    const float* W1  = (const float*)d_in[3];
    const float* b1  = (const float*)d_in[4];
    const float* W2  = (const float*)d_in[5];
    const float* b2  = (const float*)d_in[6];
    const float* W3  = (const float*)d_in[7];
    const float* b3  = (const float*)d_in[8];
    const float* Wmu = (const float*)d_in[9];
    const float* bmu = (const float*)d_in[10];
    const float* Wlv = (const float*)d_in[11];
    const float* blv = (const float*)d_in[12];
    float* out = (float*)d_out;

    const int N = in_sizes[0] / 10;
    const int E = in_sizes[1] / 2;
    const int G = out_size / 128;

    const int* src = eidx;       // edge_index[0]
    const int* dst = eidx + E;   // edge_index[1]

    // workspace carve-up (~114 MB)
    __hip_bfloat16* SA = (__hip_bfloat16*)d_ws;          // [N,256] bf16 ping
    __hip_bfloat16* SB = SA + (size_t)N * 256;           // [N,256] bf16 pong
    float* dis  = (float*)(SB + (size_t)N * 256);        // [N]
    __hip_bfloat16* W2T = (__hip_bfloat16*)(dis + N);    // [256][128]
    __hip_bfloat16* W3T = W2T + 256 * 128;               // [256][256]
    __hip_bfloat16* xd  = W3T + 256 * 256;               // [N][16] x*dis (16B-aligned)
    int* deg     = (int*)(xd + (size_t)N * 16);          // [N]
    int* row_ptr = deg + N;                              // [N+1]
    int* cursor  = row_ptr + N + 1;                      // [N]
    int* col     = cursor + N;                           // [E]
    int* goff    = col + E;                              // [G+1]
    int* bsum    = goff + G + 1;                         // [nb]

    const int ntiles = (N + 15) / 16;
    const int nb = (N + SCAN_CHUNK - 1) / SCAN_CHUNK;

    // setup: deg=1, W transposes, goff boundaries
    {
        int total = 2 * N + 128 * 256 + 256 * 256;
        setup_kernel<<<(total + THREADS - 1) / THREADS, THREADS, 0, stream>>>(
            deg, W2, W2T, W3, W3T, batch, goff, N, G);
    }
    // XCD-pinned indegree histogram (uint4 edge reads)
    hist_deg_kernel<<<2048, THREADS, 0, stream>>>(dst, deg, E, N);
    // parallel scan: partials then final (row_ptr + cursor + dis + xd pack)
    scan_part_kernel<<<nb, 1024, 0, stream>>>(deg, bsum, N);
    scan_final_kernel<<<nb, 1024, 0, stream>>>(deg, bsum, nb, row_ptr, cursor, dis, x, xd, N);
    // XCD-pinned CSR fill (uint4 edge reads)
    fill_csr_kernel<<<2048, THREADS, 0, stream>>>(src, dst, cursor, col, E, N);

    // layer 1: fused xd gather + 10->128 transform -> row-major SA [N,128]
    layer1_kernel<<<(N + 127) / 128, THREADS, 0, stream>>>(
        xd, row_ptr, col, dis, W1, b1, SA, N);

    // layer 2: aggregate S1 (128 bf16 cols) then MFMA transform 128->256 (*dis)
    agg_bf16_kernel<128, 16><<<(N + 15) / 16, THREADS, 0, stream>>>(SA, row_ptr, col, dis, SB, N);
    transform_mfma2_kernel<128, true><<<512, THREADS, 0, stream>>>(SB, W2T, b2, dis, SA, N, ntiles);

    // layer 3: aggregate S2 (256 bf16 cols) then MFMA transform 256->256
    agg_bf16_kernel<256, 32><<<(N + 7) / 8, THREADS, 0, stream>>>(SA, row_ptr, col, dis, SB, N);
    transform_mfma2_kernel<256, false><<<512, THREADS, 0, stream>>>(SB, W3T, b3, dis, SA, N, ntiles);

    // fused mean pool + heads (vectorized reads)
    pool_heads_kernel<<<G, THREADS, 0, stream>>>(SA, goff, Wmu, bmu, Wlv, blv, out, G);
}

// Round 16
// 456.807 us; speedup vs baseline: 1.4244x; 1.0458x over previous
//
#include <hip/hip_runtime.h>
#include <hip/hip_bf16.h>
#include <math.h>

// GraphEncoder: 3x GCNConv (relu) -> global_mean_pool -> two linear heads.
// N=100000, E=1600000, G=2048, feats 10->128->256->256->64(x2)
//
// Round-16: transform epilogue fix. Round-15's request model exonerated
// hist/fill/layer1/pool (-7us), re-audit found transform_mfma2's epilogue
// issues 16 SCALAR 2B stores per lane per tile (D-frag cols 16 apart) =
// 38M store-requests across both transforms (~90us at the 0.43G req/us
// ceiling). Fix: stage tile in LDS (stride 264 = conflict-free writes),
// store as 512 contiguous uint4 (8x fewer requests, coalesced).
// Everything else frozen from round 15 for clean attribution.

#define THREADS 256
#define SCAN_CHUNK 4096

typedef __attribute__((ext_vector_type(8))) short bf16x8;
typedef __attribute__((ext_vector_type(4))) float f32x4;

// ---------------- fused setup: deg=1, W2T, W3T, goff boundaries ----------------
__global__ void setup_kernel(int* deg,
                             const float* __restrict__ W2, __hip_bfloat16* __restrict__ W2T,
                             const float* __restrict__ W3, __hip_bfloat16* __restrict__ W3T,
                             const int* __restrict__ batch, int* goff,
                             int n, int g) {
    int i = blockIdx.x * blockDim.x + threadIdx.x;
    if (i < n) deg[i] = 1;                       // self-loop
    int r2 = i - n;
    if (r2 >= 0 && r2 < 128 * 256) {
        int k = r2 >> 8, c = r2 & 255;
        W2T[c * 128 + k] = __float2bfloat16(W2[r2]);
    }
    int r3 = i - n - 128 * 256;
    if (r3 >= 0 && r3 < 256 * 256) {
        int k = r3 >> 8, c = r3 & 255;
        W3T[c * 256 + k] = __float2bfloat16(W3[r3]);
    }
    int r4 = i - n - 128 * 256 - 256 * 256;
    if (r4 >= 0 && r4 < n) {
        int j = r4;
        int b = batch[j];
        if (j == 0) {
            for (int q = 0; q <= b; ++q) goff[q] = 0;
        } else {
            int bp = batch[j - 1];
            for (int q = bp + 1; q <= b; ++q) goff[q] = j;
        }
        if (j == n - 1) {
            for (int q = b + 1; q <= g; ++q) goff[q] = n;
        }
    }
}

// ---------------- XCD-pinned indegree histogram, uint4 edge reads -------------
__global__ __launch_bounds__(THREADS) void hist_deg_kernel(
        const int* __restrict__ dst, int* deg, int e, int n) {
    const int slice = blockIdx.x & 7;
    const int sliceSize = (n + 7) / 8;
    const int lo = slice * sliceSize;
    const int hi = lo + sliceSize;
    const int tid = (blockIdx.x >> 3) * blockDim.x + threadIdx.x;
    const int nthr = (gridDim.x >> 3) * blockDim.x;
    const int e4 = e >> 2;
    const uint4* dst4 = reinterpret_cast<const uint4*>(dst);
    for (int i = tid; i < e4; i += nthr) {
        uint4 dv = dst4[i];
        int dd[4] = {(int)dv.x, (int)dv.y, (int)dv.z, (int)dv.w};
#pragma unroll
        for (int q = 0; q < 4; ++q)
            if (dd[q] >= lo && dd[q] < hi) atomicAdd(&deg[dd[q]], 1);
    }
    for (int i = (e & ~3) + tid; i < e; i += nthr) {
        int d = dst[i];
        if (d >= lo && d < hi) atomicAdd(&deg[d], 1);
    }
}

// ---------------- parallel scan, phase 1: per-chunk indegree sums ----------------
__global__ __launch_bounds__(1024) void scan_part_kernel(
        const int* __restrict__ deg, int* __restrict__ bsum, int n) {
    __shared__ int ws[16];
    const int lane = threadIdx.x & 63;
    const int wid = threadIdx.x >> 6;
    int i0 = blockIdx.x * SCAN_CHUNK + threadIdx.x * 4;
    int s = 0;
#pragma unroll
    for (int q = 0; q < 4; ++q) {
        int i = i0 + q;
        if (i < n) s += deg[i] - 1;
    }
#pragma unroll
    for (int off = 32; off > 0; off >>= 1) s += __shfl_down(s, off, 64);
    if (lane == 0) ws[wid] = s;
    __syncthreads();
    if (threadIdx.x == 0) {
        int t = 0;
        for (int w = 0; w < 16; ++w) t += ws[w];
        bsum[blockIdx.x] = t;
    }
}

__device__ __forceinline__ unsigned pack2(float a, float b) {
    unsigned short ua = __builtin_bit_cast(unsigned short, __float2bfloat16(a));
    unsigned short ub = __builtin_bit_cast(unsigned short, __float2bfloat16(b));
    return (unsigned)ua | ((unsigned)ub << 16);
}

// ---------------- parallel scan, phase 2: scan + row_ptr/cursor/dis + xd pack ----
__global__ __launch_bounds__(1024) void scan_final_kernel(
        const int* __restrict__ deg, const int* __restrict__ bsum, int nb,
        int* __restrict__ row_ptr, int* __restrict__ cursor,
        float* __restrict__ dis, const float* __restrict__ x,
        __hip_bfloat16* __restrict__ xd, int n) {
    __shared__ int wsum[16];
    __shared__ int sbase;
    const int lane = threadIdx.x & 63;
    const int wid = threadIdx.x >> 6;
    if (threadIdx.x == 0) {
        int t = 0;
        for (int b = 0; b < blockIdx.x; ++b) t += bsum[b];
        sbase = t;
        if (blockIdx.x == 0) {
            int tot = 0;
            for (int b = 0; b < nb; ++b) tot += bsum[b];
            row_ptr[n] = tot;
        }
    }
    int i0 = blockIdx.x * SCAN_CHUNK + threadIdx.x * 4;
    int v[4];
#pragma unroll
    for (int q = 0; q < 4; ++q) {
        int i = i0 + q;
        v[q] = (i < n) ? (deg[i] - 1) : 0;
    }
    int tsum = v[0] + v[1] + v[2] + v[3];
    int incl = tsum;
#pragma unroll
    for (int off = 1; off < 64; off <<= 1) {
        int t = __shfl_up(incl, off, 64);
        if (lane >= off) incl += t;
    }
    if (lane == 63) wsum[wid] = incl;
    __syncthreads();
    int wbase = 0;
    for (int w = 0; w < wid; ++w) wbase += wsum[w];
    int pos = incl - tsum + wbase + sbase;
    uint4* xd4 = reinterpret_cast<uint4*>(xd);
#pragma unroll
    for (int q = 0; q < 4; ++q) {
        int i = i0 + q;
        if (i < n) {
            row_ptr[i] = pos;
            cursor[i] = pos;
            float dv = rsqrtf((float)(v[q] + 1));
            dis[i] = dv;
            unsigned ow[8];
#pragma unroll
            for (int k = 0; k < 5; ++k)
                ow[k] = pack2(x[(size_t)i * 10 + 2 * k] * dv,
                              x[(size_t)i * 10 + 2 * k + 1] * dv);
            ow[5] = 0; ow[6] = 0; ow[7] = 0;
            xd4[(size_t)i * 2]     = make_uint4(ow[0], ow[1], ow[2], ow[3]);
            xd4[(size_t)i * 2 + 1] = make_uint4(ow[4], ow[5], ow[6], ow[7]);
        }
        pos += v[q];
    }
}

// ---------------- XCD-pinned CSR fill, uint4 edge reads ----------------
__global__ __launch_bounds__(THREADS) void fill_csr_kernel(
        const int* __restrict__ src, const int* __restrict__ dst,
        int* cursor, int* __restrict__ col, int e, int n) {
    const int slice = blockIdx.x & 7;
    const int sliceSize = (n + 7) / 8;
    const int lo = slice * sliceSize;
    const int hi = lo + sliceSize;
    const int tid = (blockIdx.x >> 3) * blockDim.x + threadIdx.x;
    const int nthr = (gridDim.x >> 3) * blockDim.x;
    const int e4 = e >> 2;
    const uint4* dst4 = reinterpret_cast<const uint4*>(dst);
    const uint4* src4 = reinterpret_cast<const uint4*>(src);
    for (int i = tid; i < e4; i += nthr) {
        uint4 dv = dst4[i];
        int dd[4] = {(int)dv.x, (int)dv.y, (int)dv.z, (int)dv.w};
        bool any = false;
#pragma unroll
        for (int q = 0; q < 4; ++q) any |= (dd[q] >= lo && dd[q] < hi);
        if (!any) continue;
        uint4 sv = src4[i];
        int ss[4] = {(int)sv.x, (int)sv.y, (int)sv.z, (int)sv.w};
#pragma unroll
        for (int q = 0; q < 4; ++q) {
            if (dd[q] >= lo && dd[q] < hi) {
                int pos = atomicAdd(&cursor[dd[q]], 1);
                col[pos] = ss[q];
            }
        }
    }
    for (int i = (e & ~3) + tid; i < e; i += nthr) {
        int d = dst[i];
        if (d >= lo && d < hi) {
            int pos = atomicAdd(&cursor[d], 1);
            col[pos] = src[i];
        }
    }
}

// ---------------- bf16 helpers ----------------
__device__ __forceinline__ void acc8(float* acc, uint4 v) {
    acc[0] += __uint_as_float(v.x << 16);
    acc[1] += __uint_as_float(v.x & 0xffff0000u);
    acc[2] += __uint_as_float(v.y << 16);
    acc[3] += __uint_as_float(v.y & 0xffff0000u);
    acc[4] += __uint_as_float(v.z << 16);
    acc[5] += __uint_as_float(v.z & 0xffff0000u);
    acc[6] += __uint_as_float(v.w << 16);
    acc[7] += __uint_as_float(v.w & 0xffff0000u);
}

// ---------------- fused layer 1: 2-lane uint4 xd gather + 10->128 transform ----
__global__ __launch_bounds__(THREADS) void layer1_kernel(
        const __hip_bfloat16* __restrict__ xd, const int* __restrict__ row_ptr,
        const int* __restrict__ col, const float* __restrict__ dis,
        const float* __restrict__ W1, const float* __restrict__ b1,
        __hip_bfloat16* __restrict__ out, int n) {
    __shared__ float h[128][12];
    __shared__ float w[10][128];
    __shared__ float bias[128];

    for (int idx = threadIdx.x; idx < 1280; idx += THREADS)
        w[idx >> 7][idx & 127] = W1[idx];
    if (threadIdx.x < 128) bias[threadIdx.x] = b1[threadIdx.x];

    const int node0 = blockIdx.x * 128;
    const int nl = threadIdx.x >> 1;
    const int lane = threadIdx.x & 1;
    const int node = node0 + nl;
    const uint4* S4 = reinterpret_cast<const uint4*>(xd);

    if (node < n) {
        float acc[8];
#pragma unroll
        for (int q = 0; q < 8; ++q) acc[q] = 0.f;
        acc8(acc, S4[(size_t)node * 2 + lane]);   // self (xd = x*dis)

        int s = row_ptr[node], e = row_ptr[node + 1];
        int p = s;
        for (; p + 8 <= e; p += 8) {
            int j[8];
#pragma unroll
            for (int q = 0; q < 8; ++q) j[q] = col[p + q];
            uint4 v[8];
#pragma unroll
            for (int q = 0; q < 8; ++q) v[q] = S4[(size_t)j[q] * 2 + lane];
#pragma unroll
            for (int q = 0; q < 8; ++q) acc8(acc, v[q]);
        }
        for (; p < e; ++p) acc8(acc, S4[(size_t)col[p] * 2 + lane]);

        float dn = dis[node];
        if (lane == 0) {
#pragma unroll
            for (int q = 0; q < 8; ++q) h[nl][q] = acc[q] * dn;
        } else {
            h[nl][8] = acc[0] * dn;
            h[nl][9] = acc[1] * dn;
        }
    }
    __syncthreads();

    const int half = threadIdx.x & 1;
    const int nodeB = node0 + (threadIdx.x >> 1);
    if (nodeB < n) {
        float dnB = dis[nodeB];
        float hv[10];
#pragma unroll
        for (int k = 0; k < 10; ++k) hv[k] = h[threadIdx.x >> 1][k];
#pragma unroll
        for (int step = 0; step < 8; ++step) {
            int c0 = half * 64 + step * 8;
            unsigned rr[4];
#pragma unroll
            for (int cc = 0; cc < 8; cc += 2) {
                float a0 = bias[c0 + cc], a1 = bias[c0 + cc + 1];
#pragma unroll
                for (int k = 0; k < 10; ++k) {
                    a0 = fmaf(hv[k], w[k][c0 + cc], a0);
                    a1 = fmaf(hv[k], w[k][c0 + cc + 1], a1);
                }
                rr[cc >> 1] = pack2(fmaxf(a0, 0.f) * dnB, fmaxf(a1, 0.f) * dnB);
            }
            reinterpret_cast<uint4*>(out)[((size_t)nodeB * 128 + c0) >> 3] =
                make_uint4(rr[0], rr[1], rr[2], rr[3]);
        }
    }
}

// ---------------- agg over COLS-col bf16 rows; L = COLS/8 lanes/node (row-major) ----
template <int COLS, int L>
__global__ __launch_bounds__(THREADS) void agg_bf16_kernel(
        const __hip_bfloat16* __restrict__ S, const int* __restrict__ row_ptr,
        const int* __restrict__ col, const float* __restrict__ dis,
        __hip_bfloat16* __restrict__ out, int n) {
    static_assert(L * 8 == COLS, "");
    constexpr int stride = COLS / 8;       // uint4 per row
    int node = blockIdx.x * (THREADS / L) + threadIdx.x / L;
    if (node >= n) return;
    int lane = threadIdx.x % L;
    const uint4* S4 = reinterpret_cast<const uint4*>(S);

    float acc[8];
#pragma unroll
    for (int q = 0; q < 8; ++q) acc[q] = 0.f;
    acc8(acc, S4[(size_t)node * stride + lane]);   // self-loop term

    int s = row_ptr[node], e = row_ptr[node + 1];
    int p = s;
    for (; p + 8 <= e; p += 8) {
        int j[8];
#pragma unroll
        for (int q = 0; q < 8; ++q) j[q] = col[p + q];
        uint4 v[8];
#pragma unroll
        for (int q = 0; q < 8; ++q) v[q] = S4[(size_t)j[q] * stride + lane];
#pragma unroll
        for (int q = 0; q < 8; ++q) acc8(acc, v[q]);
    }
    for (; p + 2 <= e; p += 2) {
        int j0 = col[p], j1 = col[p + 1];
        uint4 v0 = S4[(size_t)j0 * stride + lane];
        uint4 v1 = S4[(size_t)j1 * stride + lane];
        acc8(acc, v0); acc8(acc, v1);
    }
    for (; p < e; ++p) acc8(acc, S4[(size_t)col[p] * stride + lane]);

    float d = dis[node];
    uint4 o;
    o.x = pack2(acc[0] * d, acc[1] * d);
    o.y = pack2(acc[2] * d, acc[3] * d);
    o.z = pack2(acc[4] * d, acc[5] * d);
    o.w = pack2(acc[6] * d, acc[7] * d);
    reinterpret_cast<uint4*>(out)[(size_t)node * stride + lane] = o;
}

// ---------------- MFMA transform v3: LDS-staged vectorized epilogue ----------
// tile stride 264 bf16: row offset = 528B = 4-bank rotation -> the 16 b16
// writes/lane land 2 lanes/bank (free, m136). Full tile stored as 512
// contiguous uint4 (8KB block of row-major out), 8x fewer store requests.
template <int K, bool SCALE>
__global__ __launch_bounds__(THREADS) void transform_mfma2_kernel(
        const __hip_bfloat16* __restrict__ A, const __hip_bfloat16* __restrict__ WT,
        const float* __restrict__ b, const float* __restrict__ dis,
        __hip_bfloat16* __restrict__ out, int n, int ntiles) {
    constexpr int KS = K / 32;             // 4 (K=128) or 8 (K=256)
    constexpr int TSTR = 264;              // LDS tile row stride (bf16)
    __shared__ __hip_bfloat16 tile[16 * TSTR];
    const int wave = threadIdx.x >> 6;
    const int lane = threadIdx.x & 63;
    const int lrow = lane & 15;
    const int lk8  = (lane >> 4) * 8;      // k-element offset within a 32-k step

    const uint4* WT4 = reinterpret_cast<const uint4*>(WT);
    bf16x8 bfr[4][KS];
    float bias[4];
#pragma unroll
    for (int ct = 0; ct < 4; ++ct) {
        int colc = wave * 64 + ct * 16 + lrow;
        bias[ct] = b[colc];
#pragma unroll
        for (int kk = 0; kk < KS; ++kk)
            bfr[ct][kk] = __builtin_bit_cast(
                bf16x8, WT4[((size_t)colc * K + kk * 32 + lk8) >> 3]);
    }

    const uint4* A4 = reinterpret_cast<const uint4*>(A);
    auto loadA = [&](int t, uint4* av) {
        int row = t * 16 + lrow;
        if (row >= n) row = n - 1;
#pragma unroll
        for (int kk = 0; kk < KS; ++kk)
            av[kk] = A4[((size_t)row * K + kk * 32 + lk8) >> 3];
    };

    uint4 aC[KS], aN[KS];
    int t = blockIdx.x;
    if (t < ntiles) loadA(t, aC);

    for (; t < ntiles; t += gridDim.x) {
        int tn = t + gridDim.x;
        if (tn < ntiles) loadA(tn, aN);    // prefetch next tile

        f32x4 acc[4];
#pragma unroll
        for (int ct = 0; ct < 4; ++ct) acc[ct] = (f32x4){0.f, 0.f, 0.f, 0.f};
#pragma unroll
        for (int kk = 0; kk < KS; ++kk) {
            bf16x8 af = __builtin_bit_cast(bf16x8, aC[kk]);
#pragma unroll
            for (int ct = 0; ct < 4; ++ct)
                acc[ct] = __builtin_amdgcn_mfma_f32_16x16x32_bf16(af, bfr[ct][kk], acc[ct], 0, 0, 0);
        }

        // epilogue -> LDS tile (bias + relu + optional dis)
        const int lrow0 = (lane >> 4) * 4;         // local row base 0..12
        float dv[4];
#pragma unroll
        for (int r = 0; r < 4; ++r) {
            int rr = t * 16 + lrow0 + r;
            dv[r] = SCALE ? ((rr < n) ? dis[rr] : 0.f) : 1.f;
        }
#pragma unroll
        for (int ct = 0; ct < 4; ++ct) {
            int colc = wave * 64 + ct * 16 + lrow;
#pragma unroll
            for (int r = 0; r < 4; ++r) {
                float v = fmaxf(acc[ct][r] + bias[ct], 0.f);
                if (SCALE) v *= dv[r];
                tile[(lrow0 + r) * TSTR + colc] = __float2bfloat16(v);
            }
        }
        __syncthreads();

        // vectorized tile store: 512 uint4, coalesced
        const int base = t * 16;
        if (base + 16 <= n) {
            uint4* g = reinterpret_cast<uint4*>(out + (size_t)base * 256);
            const uint4* tl = reinterpret_cast<const uint4*>(tile);
#pragma unroll
            for (int h = 0; h < 2; ++h) {
                int idx = threadIdx.x + h * 256;       // 0..511
                int row = idx >> 5, c16 = idx & 31;
                g[idx] = tl[row * (TSTR / 8) + c16];
            }
        } else {
            for (int idx = threadIdx.x; idx < 16 * 256; idx += THREADS) {
                int rr = base + (idx >> 8);
                if (rr < n) out[(size_t)rr * 256 + (idx & 255)] = tile[(idx >> 8) * TSTR + (idx & 255)];
            }
        }
        __syncthreads();

#pragma unroll
        for (int kk = 0; kk < KS; ++kk) aC[kk] = aN[kk];
    }
}

// ---------------- fused mean-pool + heads, uint4 H reads ----------------
__global__ __launch_bounds__(THREADS) void pool_heads_kernel(
        const __hip_bfloat16* __restrict__ H, const int* __restrict__ goff,
        const float* __restrict__ Wmu, const float* __restrict__ bmu,
        const float* __restrict__ Wlv, const float* __restrict__ blv,
        float* __restrict__ out, int g_total) {
    __shared__ float part[8][256];
    __shared__ float p[256];
    int g = blockIdx.x;
    int s = goff[g], e = goff[g + 1];
    int rgrp = threadIdx.x >> 5;
    int lane = threadIdx.x & 31;
    const uint4* H4 = reinterpret_cast<const uint4*>(H);

    float acc[8];
#pragma unroll
    for (int q = 0; q < 8; ++q) acc[q] = 0.f;
    for (int r = s + rgrp; r < e; r += 8)
        acc8(acc, H4[(size_t)r * 32 + lane]);
#pragma unroll
    for (int q = 0; q < 8; ++q) part[rgrp][lane * 8 + q] = acc[q];
    __syncthreads();

    int c = threadIdx.x;
    float t = 0.f;
#pragma unroll
    for (int gq = 0; gq < 8; ++gq) t += part[gq][c];
    p[c] = t / fmaxf((float)(e - s), 1.0f);
    __syncthreads();

    if (threadIdx.x < 128) {
        int cc = threadIdx.x & 63;
        bool is_mu = threadIdx.x < 64;
        const float* W = is_mu ? Wmu : Wlv;
        const float* bb = is_mu ? bmu : blv;
        float a = 0.f;
        for (int k = 0; k < 256; ++k) a = fmaf(p[k], W[k * 64 + cc], a);
        float* o = is_mu ? (out + (size_t)g * 64)
                         : (out + (size_t)g_total * 64 + (size_t)g * 64);
        o[cc] = a + bb[cc];
    }
}

extern "C" void kernel_launch(void* const* d_in, const int* in_sizes, int n_in,
                              void* d_out, int out_size, void* d_ws, size_t ws_size,
                              hipStream_t stream) {
    const float* x      = (const float*)d_in[0];
    const int*   eidx   = (const int*)d_in[1];
    const int*   batch  = (const int*)d_in[2];
    const float* W1  = (const float*)d_in[3];
    const float* b1  = (const float*)d_in[4];
    const float* W2  = (const float*)d_in[5];
    const float* b2  = (const float*)d_in[6];
    const float* W3  = (const float*)d_in[7];
    const float* b3  = (const float*)d_in[8];
    const float* Wmu = (const float*)d_in[9];
    const float* bmu = (const float*)d_in[10];
    const float* Wlv = (const float*)d_in[11];
    const float* blv = (const float*)d_in[12];
    float* out = (float*)d_out;

    const int N = in_sizes[0] / 10;
    const int E = in_sizes[1] / 2;
    const int G = out_size / 128;

    const int* src = eidx;       // edge_index[0]
    const int* dst = eidx + E;   // edge_index[1]

    // workspace carve-up (~114 MB)
    __hip_bfloat16* SA = (__hip_bfloat16*)d_ws;          // [N,256] bf16 ping
    __hip_bfloat16* SB = SA + (size_t)N * 256;           // [N,256] bf16 pong
    float* dis  = (float*)(SB + (size_t)N * 256);        // [N]
    __hip_bfloat16* W2T = (__hip_bfloat16*)(dis + N);    // [256][128]
    __hip_bfloat16* W3T = W2T + 256 * 128;               // [256][256]
    __hip_bfloat16* xd  = W3T + 256 * 256;               // [N][16] x*dis (16B-aligned)
    int* deg     = (int*)(xd + (size_t)N * 16);          // [N]
    int* row_ptr = deg + N;                              // [N+1]
    int* cursor  = row_ptr + N + 1;                      // [N]
    int* col     = cursor + N;                           // [E]
    int* goff    = col + E;                              // [G+1]
    int* bsum    = goff + G + 1;                         // [nb]

    const int ntiles = (N + 15) / 16;
    const int nb = (N + SCAN_CHUNK - 1) / SCAN_CHUNK;

    // setup: deg=1, W transposes, goff boundaries
    {
        int total = 2 * N + 128 * 256 + 256 * 256;
        setup_kernel<<<(total + THREADS - 1) / THREADS, THREADS, 0, stream>>>(
            deg, W2, W2T, W3, W3T, batch, goff, N, G);
    }
    // XCD-pinned indegree histogram (uint4 edge reads)
    hist_deg_kernel<<<2048, THREADS, 0, stream>>>(dst, deg, E, N);
    // parallel scan: partials then final (row_ptr + cursor + dis + xd pack)
    scan_part_kernel<<<nb, 1024, 0, stream>>>(deg, bsum, N);
    scan_final_kernel<<<nb, 1024, 0, stream>>>(deg, bsum, nb, row_ptr, cursor, dis, x, xd, N);
    // XCD-pinned CSR fill (uint4 edge reads)
    fill_csr_kernel<<<2048, THREADS, 0, stream>>>(src, dst, cursor, col, E, N);

    // layer 1: fused xd gather + 10->128 transform -> row-major SA [N,128]
    layer1_kernel<<<(N + 127) / 128, THREADS, 0, stream>>>(
        xd, row_ptr, col, dis, W1, b1, SA, N);

    // layer 2: aggregate S1 (128 bf16 cols) then MFMA transform 128->256 (*dis)
    agg_bf16_kernel<128, 16><<<(N + 15) / 16, THREADS, 0, stream>>>(SA, row_ptr, col, dis, SB, N);
    transform_mfma2_kernel<128, true><<<512, THREADS, 0, stream>>>(SB, W2T, b2, dis, SA, N, ntiles);

    // layer 3: aggregate S2 (256 bf16 cols) then MFMA transform 256->256
    agg_bf16_kernel<256, 32><<<(N + 7) / 8, THREADS, 0, stream>>>(SA, row_ptr, col, dis, SB, N);
    transform_mfma2_kernel<256, false><<<512, THREADS, 0, stream>>>(SB, W3T, b3, dis, SA, N, ntiles);

    // fused mean pool + heads (vectorized reads)
    pool_heads_kernel<<<G, THREADS, 0, stream>>>(SA, goff, Wmu, bmu, Wlv, blv, out, G);
}